// Round 15
// baseline (379.249 us; speedup 1.0000x reference)
//
#include <hip/hip_runtime.h>

#define T_STEPS 100
#define NTRAJ   8192
#define MBLK    32     // two 16-row tile groups per block
#define W_TILES 112
#define W_BYTES (W_TILES * 1024)            // 114688: G1/G3/G4/G5 weights in LDS
#define TILEBUF 18432                       // per-group activation buffers
#define LDS_TOTAL (W_BYTES + 2 * TILEBUF)   // 151552 <= 163840

typedef __attribute__((ext_vector_type(8))) _Float16 f16x8;
typedef __attribute__((ext_vector_type(4))) _Float16 f16x4;
typedef __attribute__((ext_vector_type(2))) __fp16   h16x2;   // cvt_pkrtz return type
typedef __attribute__((ext_vector_type(4))) float    f32x4;

#define MFMA16(a, b, c) __builtin_amdgcn_mfma_f32_16x16x32_f16((a), (b), (c), 0, 0, 0)

// XOR swizzle on element index within a row (2B elems; XOR elem bits 3..5)
#define SWZ(row, col) ((col) ^ (((row) & 7) << 3))

// LDS-only barrier: drain ds ops (lgkmcnt) but leave global x-prefetch
// (vmcnt) outstanding across the barrier. No loop vmem feeds LDS.
// (Validated for correctness in rounds 12/13.)
#define BAR() do { \
    asm volatile("s_waitcnt lgkmcnt(0)" ::: "memory"); \
    __builtin_amdgcn_s_barrier(); \
    asm volatile("" ::: "memory"); \
} while (0)

__device__ __forceinline__ float fast_tanh(float x) {
    float e = exp2f(x * 2.885390081777927f);           // exp(2x)
    return 1.f - 2.f * __builtin_amdgcn_rcpf(1.f + e);
}
__device__ __forceinline__ float fast_sigmoid(float x) {
    float e = exp2f(x * -1.4426950408889634f);         // exp(-x)
    return __builtin_amdgcn_rcpf(1.f + e);
}

// ---------------------------------------------------------------------------
// Weight packing (UNCHANGED): tile = 512 f16, element (lane, j) = W[k][n],
// k = kt*32 + (lane>>4)*8 + j, n = nt*16 + (lane&15). A-operand of W^T.
//   [0,14) G1 | [14,30) G2 | [30,75) G3 | [75,107) G4 | [107,128) G5 | [128,144) G6
// ---------------------------------------------------------------------------
__global__ void pack_kernel(const float* __restrict__ Wo1, const float* __restrict__ Wo2,
                            const float* __restrict__ Wz1, const float* __restrict__ Wz2,
                            const float* __restrict__ Wr1, const float* __restrict__ Wr2,
                            const float* __restrict__ Wh1, const float* __restrict__ Wh2,
                            _Float16* __restrict__ P)
{
    int idx = blockIdx.x * 256 + threadIdx.x;
    if (idx >= 144 * 512) return;
    int tile = idx >> 9;
    int r    = idx & 511;
    int lane = r >> 3, j = r & 7;
    int krel = ((lane >> 4) << 3) + j;   // 0..31
    int c16  = lane & 15;
    float val = 0.f;

    if (tile < 14) {                       // ODE L1
        int t = tile, nt = t >> 1, kt = t & 1;
        int k = kt * 32 + krel, n = nt * 16 + c16;
        if (k < 64 && n < 100) val = Wo1[k * 100 + n];
    } else if (tile < 30) {                // ODE L2
        int t = tile - 14, nt = t >> 2, kt = t & 3;
        int k = kt * 32 + krel, n = nt * 16 + c16;
        if (k < 100) val = Wo2[k * 64 + n];
    } else if (tile < 75) {                // ZR L1
        int t = tile - 30, nt = t / 3, kt = t % 3;
        int k = kt * 32 + krel;            // K = 96 exact
        if (nt < 7)      { int n = nt * 16 + c16;        if (n < 100) val = Wz1[k * 100 + n]; }
        else if (nt >= 8){ int n = (nt - 8) * 16 + c16;  if (n < 100) val = Wr1[k * 100 + n]; }
    } else if (tile < 107) {               // ZR L2
        int t = tile - 75, gate = t >> 4, rem = t & 15, nt = rem >> 2, kt = rem & 3;
        int k = kt * 32 + krel, n = nt * 16 + c16;
        const float* W = gate ? Wr2 : Wz2;
        if (k < 100) val = W[k * 64 + n];
    } else if (tile < 128) {               // H L1
        int t = tile - 107, nt = t / 3, kt = t % 3;
        int k = kt * 32 + krel, n = nt * 16 + c16;
        if (n < 100) val = Wh1[k * 100 + n];
    } else {                               // H L2
        int t = tile - 128, nt = t >> 2, kt = t & 3;
        int k = kt * 32 + krel, n = nt * 16 + c16;
        if (k < 100) val = Wh2[k * 64 + n];
    }
    P[idx] = (_Float16)val;
}

// activation B-fragment read: n = traj = lane&15, k-slice contiguous 8
__device__ __forceinline__ f16x8 ldsA(const _Float16* buf, int stride, int row, int kcol) {
    return *(const f16x8*)(buf + row * stride + SWZ(row, kcol));
}
// contiguous 4-feature epilogue store (one b64)
__device__ __forceinline__ void st4(_Float16* buf, int stride, int traj, int f0,
                                    float a, float b, float c, float d) {
    f16x4 h = {(_Float16)a, (_Float16)b, (_Float16)c, (_Float16)d};
    *(f16x4*)(buf + traj * stride + SWZ(traj, f0)) = h;
}
__device__ __forceinline__ f32x4 loadBias4(const float* b, int f0, int n) {
    f32x4 v = {0.f, 0.f, 0.f, 0.f};
    #pragma unroll
    for (int r = 0; r < 4; ++r) if (f0 + r < n) v[r] = b[f0 + r];
    return v;
}
// pack 8 f32 (two f32x4) -> f16x8 via cvt_pkrtz
__device__ __forceinline__ f16x8 cvt8(f32x4 a, f32x4 b) {
    union { h16x2 h2[4]; f16x8 v; } u;
    u.h2[0] = __builtin_amdgcn_cvt_pkrtz(a[0], a[1]);
    u.h2[1] = __builtin_amdgcn_cvt_pkrtz(a[2], a[3]);
    u.h2[2] = __builtin_amdgcn_cvt_pkrtz(b[0], b[1]);
    u.h2[3] = __builtin_amdgcn_cvt_pkrtz(b[2], b[3]);
    return u.v;
}

// ---------------------------------------------------------------------------
// R11 structure EXACTLY (best verified: 299us, weights in LDS, 8 reg frags,
// 96 VGPR) + two isolated micro-opts:
//   1. lgkmcnt-only barriers -> x prefetch floats across the whole step
//   2. exp2-form activations (-1 VALU per tanh/sigmoid)
// Register-resident-weights thesis abandoned: 128-arch-VGPR cap is hard
// for this kernel (R12/R13 evidence).
// ---------------------------------------------------------------------------
__global__ __launch_bounds__(512, 2) void odernn_kernel(
    const float* __restrict__ data, const float* __restrict__ ts,
    const float* __restrict__ prior,
    const float* __restrict__ bo1, const float* __restrict__ bo2,
    const float* __restrict__ bz1, const float* __restrict__ bz2,
    const float* __restrict__ br1, const float* __restrict__ br2,
    const float* __restrict__ bh1, const float* __restrict__ bh2,
    const _Float16* __restrict__ P, float* __restrict__ out)
{
    extern __shared__ __align__(16) char smem[];
    _Float16* W = (_Float16*)smem;        // 112 tiles: G1[0,14) G3[14,59) G4[59,91) G5[91,112)

    const int tid  = threadIdx.x;
    const int lane = tid & 63;
    const int wv   = tid >> 6;            // 0..7
    const int tg   = wv >> 2;             // tile group 0/1
    const int wq   = wv & 3;              // wave-in-group
    const int c16  = lane & 15;           // trajectory within group
    const int g4   = lane >> 4;
    const int m0   = blockIdx.x * MBLK + tg * 16;
    const int f0   = wq * 16 + (g4 << 2); // lane's own 4-feature base (tile nt=wq)
    const f16x8* Pt = (const f16x8*)P;
    const f16x8* Wv = (const f16x8*)W;

    _Float16* base = (_Float16*)(smem + W_BYTES + tg * TILEBUF);
    _Float16* sYb = base;                 // [16][64]  y
    _Float16* sYX = base + 1024;          // [16][64]  yode
    _Float16* sRX = base + 2048;          // [16][64]  rg*yode
    _Float16* sH1 = base + 3072;          // [16][128] hidden
    _Float16* sZR = base + 5120;          // [16][256] [zh|rh] + pads

    // ---- stage G1/G3/G4/G5 weights into LDS ----
    {
        f16x8* Wd = (f16x8*)W;
        #pragma unroll
        for (int it = 0; it < 14; ++it) {
            int idx = tid + it * 512;
            int ldst = idx >> 6, l = idx & 63;
            int srct = (ldst < 14) ? ldst : ldst + 16;   // skip G2 range
            Wd[idx] = Pt[srct * 64 + l];
        }
    }

    // ---- G3/G5 tile indices for this wave ----
    int bt3[4];
    #pragma unroll
    for (int q = 0; q < 4; ++q) {
        int i = wq + 4 * q;
        bt3[q] = (i < 14) ? ((i < 7) ? i : i + 1) : 0;
    }

    // ---- biases as per-lane f32x4 feature vectors ----
    f32x4 bo1v[2], bh1v[2], bzrv[4];
    #pragma unroll
    for (int t = 0; t < 2; ++t) {
        int nt = wq + 4 * t;
        f32x4 zo = {0.f,0.f,0.f,0.f};
        if (nt < 7) {
            int ft = nt * 16 + (g4 << 2);
            bo1v[t] = loadBias4(bo1, ft, 100);
            bh1v[t] = loadBias4(bh1, ft, 100);
        } else { bo1v[t] = zo; bh1v[t] = zo; }
    }
    #pragma unroll
    for (int q = 0; q < 4; ++q) {
        int i = wq + 4 * q;
        f32x4 v = {0.f,0.f,0.f,0.f};
        if (i < 14) {
            int ft = bt3[q] * 16 + (g4 << 2);
            if (i < 7) v = loadBias4(bz1, ft, 100);
            else       v = loadBias4(br1, ft - 128, 100);
        }
        bzrv[q] = v;
    }
    const f32x4 bo2v = *(const f32x4*)(bo2 + f0);
    const f32x4 bz2v = *(const f32x4*)(bz2 + f0);
    const f32x4 br2v = *(const f32x4*)(br2 + f0);
    const f32x4 bh2v = *(const f32x4*)(bh2 + f0);

    // ---- register A-frags (weights) for short dependent phases G2/G6 ----
    f16x8 Ao2[4], Ah2[4];
    #pragma unroll
    for (int kt = 0; kt < 4; ++kt) {
        Ao2[kt] = Pt[(14 + wq * 4 + kt) * 64 + lane];
        Ah2[kt] = Pt[(128 + wq * 4 + kt) * 64 + lane];
    }

    // ---- init state ----
    float y[4], yo[4] = {0,0,0,0}, zg[4] = {0,0,0,0};
    {
        f32x4 pv = *(const f32x4*)(prior + (size_t)(m0 + c16) * 64 + f0);
        #pragma unroll
        for (int r = 0; r < 4; ++r) y[r] = pv[r];
        st4(sYb, 64, c16, f0, y[0], y[1], y[2], y[3]);
    }
    {   // sH1 pad feats 112..127, both groups (512 elems, 1/thread)
        int row32 = tid >> 4, col = 112 + (tid & 15);
        int t = row32 >> 4, r16 = row32 & 15;
        _Float16* h1 = (_Float16*)(smem + W_BYTES + t * TILEBUF) + 3072;
        h1[r16 * 128 + SWZ(r16, col)] = (_Float16)0.f;
    }
    for (int i = tid; i < 2 * 16 * 32; i += 512) {   // sZR pads, both groups
        int t = i >> 9, rem = i & 511;
        int r16 = rem >> 5, cc = rem & 31;
        int col = (cc < 16) ? (112 + cc) : (224 + cc);
        _Float16* zr = (_Float16*)(smem + W_BYTES + t * TILEBUF) + 5120;
        zr[r16 * 256 + SWZ(r16, col)] = (_Float16)0.f;
    }
    __syncthreads();

    const float t0v = ts[0], t1v = ts[1];

    // ---- x fragment: lane owns x[traj=c16][feat g4*8 .. g4*8+7] ----
    const float* xptr = data + (size_t)(m0 + c16) * (T_STEPS * 32) + 32 + (g4 << 3);
    f32x4 xn0 = *(const f32x4*)(xptr);
    f32x4 xn1 = *(const f32x4*)(xptr + 4);
    f16x8 xfrag = cvt8(xn0, xn1);

    #pragma unroll 1
    for (int s = 0; s < T_STEPS - 1; ++s) {
        const float dt = (s == 0) ? (t1v - t0v) : (ts[s - 1] - ts[s]);

        // ---- slot 1: prefetch next x; G1; xacc3 (G3 x-partials) ----
        xptr += 32;
        if (s < T_STEPS - 2) {
            xn0 = *(const f32x4*)(xptr);
            xn1 = *(const f32x4*)(xptr + 4);
        }
        f32x4 xacc3[4];
        {
            f16x8 b0 = ldsA(sYb, 64, c16, (g4 << 3));
            f16x8 b1 = ldsA(sYb, 64, c16, 32 + (g4 << 3));
            #pragma unroll
            for (int t = 0; t < 2; ++t) {
                int nt = wq + 4 * t;
                if (nt < 7) {
                    f32x4 acc0 = bo1v[t];
                    f32x4 z4 = {0.f, 0.f, 0.f, 0.f};
                    acc0 = MFMA16(Wv[(nt * 2 + 0) * 64 + lane], b0, acc0);
                    f32x4 acc1 = MFMA16(Wv[(nt * 2 + 1) * 64 + lane], b1, z4);
                    int ft = nt * 16 + (g4 << 2);
                    st4(sH1, 128, c16, ft,
                        fast_tanh(acc0[0] + acc1[0]), fast_tanh(acc0[1] + acc1[1]),
                        fast_tanh(acc0[2] + acc1[2]), fast_tanh(acc0[3] + acc1[3]));
                }
            }
            #pragma unroll
            for (int q = 0; q < 4; ++q) {
                int i = wq + 4 * q;
                if (i < 14) xacc3[q] = MFMA16(Pt[(30 + bt3[q] * 3 + 2) * 64 + lane], xfrag, bzrv[q]);
            }
        }
        BAR();

        // ---- slot 2: G2 (yode) + xacc5 (G5 x-partials) ----
        f32x4 xacc5[2];
        {
            f32x4 acc0 = bo2v;
            f32x4 z4 = {0.f, 0.f, 0.f, 0.f};
            acc0 = MFMA16(Ao2[0], ldsA(sH1, 128, c16, 0 * 32 + (g4 << 3)), acc0);
            f32x4 acc1 = MFMA16(Ao2[1], ldsA(sH1, 128, c16, 1 * 32 + (g4 << 3)), z4);
            acc0 = MFMA16(Ao2[2], ldsA(sH1, 128, c16, 2 * 32 + (g4 << 3)), acc0);
            acc1 = MFMA16(Ao2[3], ldsA(sH1, 128, c16, 3 * 32 + (g4 << 3)), acc1);
            #pragma unroll
            for (int t = 0; t < 2; ++t) {
                int nt = wq + 4 * t;
                if (nt < 7)
                    xacc5[t] = MFMA16(Pt[(107 + nt * 3 + 2) * 64 + lane], xfrag, bh1v[t]);
            }
            #pragma unroll
            for (int r = 0; r < 4; ++r) yo[r] = y[r] + dt * (acc0[r] + acc1[r]);
            st4(sYX, 64, c16, f0, yo[0], yo[1], yo[2], yo[3]);
        }
        BAR();

        // ---- slot 3: G3 (2 MFMAs/tile, C-init = x-partial) ----
        {
            f16x8 b0 = ldsA(sYX, 64, c16, (g4 << 3));
            f16x8 b1 = ldsA(sYX, 64, c16, 32 + (g4 << 3));
            #pragma unroll
            for (int q = 0; q < 4; ++q) {
                int i = wq + 4 * q;
                if (i < 14) {
                    f32x4 acc = MFMA16(Wv[(14 + bt3[q] * 3 + 0) * 64 + lane], b0, xacc3[q]);
                    acc = MFMA16(Wv[(14 + bt3[q] * 3 + 1) * 64 + lane], b1, acc);
                    int ft = bt3[q] * 16 + (g4 << 2);
                    st4(sZR, 256, c16, ft,
                        fast_tanh(acc[0]), fast_tanh(acc[1]),
                        fast_tanh(acc[2]), fast_tanh(acc[3]));
                }
            }
        }
        BAR();

        // ---- slot 4: G4 (z-gate -> regs ; r-gate*yode -> sRX) ----
        {
            f32x4 accz0 = bz2v, accr0 = br2v;
            f32x4 z4 = {0.f, 0.f, 0.f, 0.f};
            f32x4 accz1 = z4, accr1 = z4;
            accz0 = MFMA16(Wv[(59 + wq * 4 + 0) * 64 + lane], ldsA(sZR, 256, c16, 0 * 32 + (g4 << 3)), accz0);
            accr0 = MFMA16(Wv[(75 + wq * 4 + 0) * 64 + lane], ldsA(sZR, 256, c16, 128 + 0 * 32 + (g4 << 3)), accr0);
            accz1 = MFMA16(Wv[(59 + wq * 4 + 1) * 64 + lane], ldsA(sZR, 256, c16, 1 * 32 + (g4 << 3)), accz1);
            accr1 = MFMA16(Wv[(75 + wq * 4 + 1) * 64 + lane], ldsA(sZR, 256, c16, 128 + 1 * 32 + (g4 << 3)), accr1);
            accz0 = MFMA16(Wv[(59 + wq * 4 + 2) * 64 + lane], ldsA(sZR, 256, c16, 2 * 32 + (g4 << 3)), accz0);
            accr0 = MFMA16(Wv[(75 + wq * 4 + 2) * 64 + lane], ldsA(sZR, 256, c16, 128 + 2 * 32 + (g4 << 3)), accr0);
            accz1 = MFMA16(Wv[(59 + wq * 4 + 3) * 64 + lane], ldsA(sZR, 256, c16, 3 * 32 + (g4 << 3)), accz1);
            accr1 = MFMA16(Wv[(75 + wq * 4 + 3) * 64 + lane], ldsA(sZR, 256, c16, 128 + 3 * 32 + (g4 << 3)), accr1);
            float rv[4];
            #pragma unroll
            for (int r = 0; r < 4; ++r) {
                zg[r] = fast_sigmoid(accz0[r] + accz1[r]);
                rv[r] = fast_sigmoid(accr0[r] + accr1[r]) * yo[r];
            }
            st4(sRX, 64, c16, f0, rv[0], rv[1], rv[2], rv[3]);
        }
        BAR();

        // ---- slot 5: G5 (2 MFMAs/tile, C-init = x-partial) ----
        {
            f16x8 b0 = ldsA(sRX, 64, c16, (g4 << 3));
            f16x8 b1 = ldsA(sRX, 64, c16, 32 + (g4 << 3));
            #pragma unroll
            for (int t = 0; t < 2; ++t) {
                int nt = wq + 4 * t;
                if (nt < 7) {
                    f32x4 acc = MFMA16(Wv[(91 + nt * 3 + 0) * 64 + lane], b0, xacc5[t]);
                    acc = MFMA16(Wv[(91 + nt * 3 + 1) * 64 + lane], b1, acc);
                    int ft = nt * 16 + (g4 << 2);
                    st4(sH1, 128, c16, ft,
                        fast_tanh(acc[0]), fast_tanh(acc[1]),
                        fast_tanh(acc[2]), fast_tanh(acc[3]));
                }
            }
        }
        BAR();

        // ---- slot 6: G6 (h, blend, y) ----
        {
            f32x4 acc0 = bh2v;
            f32x4 z4 = {0.f, 0.f, 0.f, 0.f};
            acc0 = MFMA16(Ah2[0], ldsA(sH1, 128, c16, 0 * 32 + (g4 << 3)), acc0);
            f32x4 acc1 = MFMA16(Ah2[1], ldsA(sH1, 128, c16, 1 * 32 + (g4 << 3)), z4);
            acc0 = MFMA16(Ah2[2], ldsA(sH1, 128, c16, 2 * 32 + (g4 << 3)), acc0);
            acc1 = MFMA16(Ah2[3], ldsA(sH1, 128, c16, 3 * 32 + (g4 << 3)), acc1);
            #pragma unroll
            for (int r = 0; r < 4; ++r) {
                float h = fast_tanh(acc0[r] + acc1[r]);
                y[r] = (1.f - zg[r]) * h + zg[r] * yo[r];
            }
            st4(sYb, 64, c16, f0, y[0], y[1], y[2], y[3]);
        }
        BAR();

        xfrag = cvt8(xn0, xn1);   // pack prefetched x for next step
    }

    {
        f32x4 ov = {y[0], y[1], y[2], y[3]};
        *(f32x4*)(out + (size_t)(m0 + c16) * 64 + f0) = ov;
    }
}

extern "C" void kernel_launch(void* const* d_in, const int* in_sizes, int n_in,
                              void* d_out, int out_size, void* d_ws, size_t ws_size,
                              hipStream_t stream) {
    const float* data = (const float*)d_in[0];
    const float* ts   = (const float*)d_in[1];
    const float* prior= (const float*)d_in[2];
    const float* Wo1 = (const float*)d_in[3];  const float* bo1 = (const float*)d_in[4];
    const float* Wo2 = (const float*)d_in[5];  const float* bo2 = (const float*)d_in[6];
    const float* Wz1 = (const float*)d_in[7];  const float* bz1 = (const float*)d_in[8];
    const float* Wz2 = (const float*)d_in[9];  const float* bz2 = (const float*)d_in[10];
    const float* Wr1 = (const float*)d_in[11]; const float* br1 = (const float*)d_in[12];
    const float* Wr2 = (const float*)d_in[13]; const float* br2 = (const float*)d_in[14];
    const float* Wh1 = (const float*)d_in[15]; const float* bh1 = (const float*)d_in[16];
    const float* Wh2 = (const float*)d_in[17]; const float* bh2 = (const float*)d_in[18];
    _Float16* P = (_Float16*)d_ws;
    float* out = (float*)d_out;

    (void)hipFuncSetAttribute((const void*)odernn_kernel,
                              hipFuncAttributeMaxDynamicSharedMemorySize, LDS_TOTAL);

    hipLaunchKernelGGL(pack_kernel, dim3((144 * 512 + 255) / 256), dim3(256), 0, stream,
                       Wo1, Wo2, Wz1, Wz2, Wr1, Wr2, Wh1, Wh2, P);
    hipLaunchKernelGGL(odernn_kernel, dim3(NTRAJ / MBLK), dim3(512), LDS_TOTAL, stream,
                       data, ts, prior, bo1, bo2, bz1, bz2, br1, br2, bh1, bh2, P, out);
}

// Round 16
// 365.372 us; speedup vs baseline: 1.0380x; 1.0380x over previous
//
#include <hip/hip_runtime.h>

#define T_STEPS 100
#define NTRAJ   8192
#define MBLK    32     // two 16-row tile groups per block
#define W_TILES 112
#define W_BYTES (W_TILES * 1024)            // 114688: G1/G3/G4/G5 weights in LDS
#define TILEBUF 18432                       // per-group activation buffers
#define LDS_TOTAL (W_BYTES + 2 * TILEBUF)   // 151552 <= 163840

typedef __attribute__((ext_vector_type(8))) _Float16 f16x8;
typedef __attribute__((ext_vector_type(4))) _Float16 f16x4;
typedef __attribute__((ext_vector_type(2))) __fp16   h16x2;   // cvt_pkrtz return type
typedef __attribute__((ext_vector_type(4))) float    f32x4;

#define MFMA16(a, b, c) __builtin_amdgcn_mfma_f32_16x16x32_f16((a), (b), (c), 0, 0, 0)

// XOR swizzle on element index within a row (2B elems; XOR elem bits 3..5)
#define SWZ(row, col) ((col) ^ (((row) & 7) << 3))

// LDS-only barrier: drain ds ops (lgkmcnt) but leave global x-prefetch
// (vmcnt) outstanding across the barrier. No loop vmem feeds LDS.
#define BAR() do { \
    asm volatile("s_waitcnt lgkmcnt(0)" ::: "memory"); \
    __builtin_amdgcn_s_barrier(); \
    asm volatile("" ::: "memory"); \
} while (0)

__device__ __forceinline__ float fast_tanh(float x) {
    float e = exp2f(x * 2.885390081777927f);           // exp(2x)
    return 1.f - 2.f * __builtin_amdgcn_rcpf(1.f + e);
}
__device__ __forceinline__ float fast_sigmoid(float x) {
    float e = exp2f(x * -1.4426950408889634f);         // exp(-x)
    return __builtin_amdgcn_rcpf(1.f + e);
}

// ---------------------------------------------------------------------------
// Weight packing (UNCHANGED): tile = 512 f16, element (lane, j) = W[k][n],
// k = kt*32 + (lane>>4)*8 + j, n = nt*16 + (lane&15). A-operand of W^T.
//   [0,14) G1 | [14,30) G2 | [30,75) G3 | [75,107) G4 | [107,128) G5 | [128,144) G6
// ---------------------------------------------------------------------------
__global__ void pack_kernel(const float* __restrict__ Wo1, const float* __restrict__ Wo2,
                            const float* __restrict__ Wz1, const float* __restrict__ Wz2,
                            const float* __restrict__ Wr1, const float* __restrict__ Wr2,
                            const float* __restrict__ Wh1, const float* __restrict__ Wh2,
                            _Float16* __restrict__ P)
{
    int idx = blockIdx.x * 256 + threadIdx.x;
    if (idx >= 144 * 512) return;
    int tile = idx >> 9;
    int r    = idx & 511;
    int lane = r >> 3, j = r & 7;
    int krel = ((lane >> 4) << 3) + j;   // 0..31
    int c16  = lane & 15;
    float val = 0.f;

    if (tile < 14) {                       // ODE L1
        int t = tile, nt = t >> 1, kt = t & 1;
        int k = kt * 32 + krel, n = nt * 16 + c16;
        if (k < 64 && n < 100) val = Wo1[k * 100 + n];
    } else if (tile < 30) {                // ODE L2
        int t = tile - 14, nt = t >> 2, kt = t & 3;
        int k = kt * 32 + krel, n = nt * 16 + c16;
        if (k < 100) val = Wo2[k * 64 + n];
    } else if (tile < 75) {                // ZR L1
        int t = tile - 30, nt = t / 3, kt = t % 3;
        int k = kt * 32 + krel;            // K = 96 exact
        if (nt < 7)      { int n = nt * 16 + c16;        if (n < 100) val = Wz1[k * 100 + n]; }
        else if (nt >= 8){ int n = (nt - 8) * 16 + c16;  if (n < 100) val = Wr1[k * 100 + n]; }
    } else if (tile < 107) {               // ZR L2
        int t = tile - 75, gate = t >> 4, rem = t & 15, nt = rem >> 2, kt = rem & 3;
        int k = kt * 32 + krel, n = nt * 16 + c16;
        const float* W = gate ? Wr2 : Wz2;
        if (k < 100) val = W[k * 64 + n];
    } else if (tile < 128) {               // H L1
        int t = tile - 107, nt = t / 3, kt = t % 3;
        int k = kt * 32 + krel, n = nt * 16 + c16;
        if (n < 100) val = Wh1[k * 100 + n];
    } else {                               // H L2
        int t = tile - 128, nt = t >> 2, kt = t & 3;
        int k = kt * 32 + krel, n = nt * 16 + c16;
        if (k < 100) val = Wh2[k * 64 + n];
    }
    P[idx] = (_Float16)val;
}

// activation B-fragment read: n = traj = lane&15, k-slice contiguous 8
__device__ __forceinline__ f16x8 ldsA(const _Float16* buf, int stride, int row, int kcol) {
    return *(const f16x8*)(buf + row * stride + SWZ(row, kcol));
}
// contiguous 4-feature epilogue store (one b64)
__device__ __forceinline__ void st4(_Float16* buf, int stride, int traj, int f0,
                                    float a, float b, float c, float d) {
    f16x4 h = {(_Float16)a, (_Float16)b, (_Float16)c, (_Float16)d};
    *(f16x4*)(buf + traj * stride + SWZ(traj, f0)) = h;
}
__device__ __forceinline__ f32x4 loadBias4(const float* b, int f0, int n) {
    f32x4 v = {0.f, 0.f, 0.f, 0.f};
    #pragma unroll
    for (int r = 0; r < 4; ++r) if (f0 + r < n) v[r] = b[f0 + r];
    return v;
}
// pack 8 f32 (two f32x4) -> f16x8 via cvt_pkrtz
__device__ __forceinline__ f16x8 cvt8(f32x4 a, f32x4 b) {
    union { h16x2 h2[4]; f16x8 v; } u;
    u.h2[0] = __builtin_amdgcn_cvt_pkrtz(a[0], a[1]);
    u.h2[1] = __builtin_amdgcn_cvt_pkrtz(a[2], a[3]);
    u.h2[2] = __builtin_amdgcn_cvt_pkrtz(b[0], b[1]);
    u.h2[3] = __builtin_amdgcn_cvt_pkrtz(b[2], b[3]);
    return u.v;
}

// ---------------------------------------------------------------------------
// R11 structure byte-identical (299us best: ALL loop weight reads from the
// LDS pool Wv; only Ao2/Ah2 in regs) + two isolated micro-opts:
//   1. lgkmcnt-only barriers (x prefetch floats across the whole step)
//   2. exp2-form activations
// R14's regression was a contaminated A/B: xacc weight reads accidentally
// hit global Pt instead of LDS Wv. Fixed here.
// ---------------------------------------------------------------------------
__global__ __launch_bounds__(512, 2) void odernn_kernel(
    const float* __restrict__ data, const float* __restrict__ ts,
    const float* __restrict__ prior,
    const float* __restrict__ bo1, const float* __restrict__ bo2,
    const float* __restrict__ bz1, const float* __restrict__ bz2,
    const float* __restrict__ br1, const float* __restrict__ br2,
    const float* __restrict__ bh1, const float* __restrict__ bh2,
    const _Float16* __restrict__ P, float* __restrict__ out)
{
    extern __shared__ __align__(16) char smem[];
    _Float16* W = (_Float16*)smem;        // 112 tiles: G1[0,14) G3[14,59) G4[59,91) G5[91,112)

    const int tid  = threadIdx.x;
    const int lane = tid & 63;
    const int wv   = tid >> 6;            // 0..7
    const int tg   = wv >> 2;             // tile group 0/1
    const int wq   = wv & 3;              // wave-in-group
    const int c16  = lane & 15;           // trajectory within group
    const int g4   = lane >> 4;
    const int m0   = blockIdx.x * MBLK + tg * 16;
    const int f0   = wq * 16 + (g4 << 2); // lane's own 4-feature base (tile nt=wq)
    const f16x8* Pt = (const f16x8*)P;
    const f16x8* Wv = (const f16x8*)W;

    _Float16* base = (_Float16*)(smem + W_BYTES + tg * TILEBUF);
    _Float16* sYb = base;                 // [16][64]  y
    _Float16* sYX = base + 1024;          // [16][64]  yode
    _Float16* sRX = base + 2048;          // [16][64]  rg*yode
    _Float16* sH1 = base + 3072;          // [16][128] hidden
    _Float16* sZR = base + 5120;          // [16][256] [zh|rh] + pads

    // ---- stage G1/G3/G4/G5 weights into LDS ----
    {
        f16x8* Wd = (f16x8*)W;
        #pragma unroll
        for (int it = 0; it < 14; ++it) {
            int idx = tid + it * 512;
            int ldst = idx >> 6, l = idx & 63;
            int srct = (ldst < 14) ? ldst : ldst + 16;   // skip G2 range
            Wd[idx] = Pt[srct * 64 + l];
        }
    }

    // ---- G3/G5 tile indices for this wave ----
    int bt3[4];
    #pragma unroll
    for (int q = 0; q < 4; ++q) {
        int i = wq + 4 * q;
        bt3[q] = (i < 14) ? ((i < 7) ? i : i + 1) : 0;
    }

    // ---- biases as per-lane f32x4 feature vectors ----
    f32x4 bo1v[2], bh1v[2], bzrv[4];
    #pragma unroll
    for (int t = 0; t < 2; ++t) {
        int nt = wq + 4 * t;
        f32x4 zo = {0.f,0.f,0.f,0.f};
        if (nt < 7) {
            int ft = nt * 16 + (g4 << 2);
            bo1v[t] = loadBias4(bo1, ft, 100);
            bh1v[t] = loadBias4(bh1, ft, 100);
        } else { bo1v[t] = zo; bh1v[t] = zo; }
    }
    #pragma unroll
    for (int q = 0; q < 4; ++q) {
        int i = wq + 4 * q;
        f32x4 v = {0.f,0.f,0.f,0.f};
        if (i < 14) {
            int ft = bt3[q] * 16 + (g4 << 2);
            if (i < 7) v = loadBias4(bz1, ft, 100);
            else       v = loadBias4(br1, ft - 128, 100);
        }
        bzrv[q] = v;
    }
    const f32x4 bo2v = *(const f32x4*)(bo2 + f0);
    const f32x4 bz2v = *(const f32x4*)(bz2 + f0);
    const f32x4 br2v = *(const f32x4*)(br2 + f0);
    const f32x4 bh2v = *(const f32x4*)(bh2 + f0);

    // ---- register A-frags (weights) for short dependent phases G2/G6 ----
    f16x8 Ao2[4], Ah2[4];
    #pragma unroll
    for (int kt = 0; kt < 4; ++kt) {
        Ao2[kt] = Pt[(14 + wq * 4 + kt) * 64 + lane];
        Ah2[kt] = Pt[(128 + wq * 4 + kt) * 64 + lane];
    }

    // ---- init state ----
    float y[4], yo[4] = {0,0,0,0}, zg[4] = {0,0,0,0};
    {
        f32x4 pv = *(const f32x4*)(prior + (size_t)(m0 + c16) * 64 + f0);
        #pragma unroll
        for (int r = 0; r < 4; ++r) y[r] = pv[r];
        st4(sYb, 64, c16, f0, y[0], y[1], y[2], y[3]);
    }
    {   // sH1 pad feats 112..127, both groups (512 elems, 1/thread)
        int row32 = tid >> 4, col = 112 + (tid & 15);
        int t = row32 >> 4, r16 = row32 & 15;
        _Float16* h1 = (_Float16*)(smem + W_BYTES + t * TILEBUF) + 3072;
        h1[r16 * 128 + SWZ(r16, col)] = (_Float16)0.f;
    }
    for (int i = tid; i < 2 * 16 * 32; i += 512) {   // sZR pads, both groups
        int t = i >> 9, rem = i & 511;
        int r16 = rem >> 5, cc = rem & 31;
        int col = (cc < 16) ? (112 + cc) : (224 + cc);
        _Float16* zr = (_Float16*)(smem + W_BYTES + t * TILEBUF) + 5120;
        zr[r16 * 256 + SWZ(r16, col)] = (_Float16)0.f;
    }
    __syncthreads();

    const float t0v = ts[0], t1v = ts[1];

    // ---- x fragment: lane owns x[traj=c16][feat g4*8 .. g4*8+7] ----
    const float* xptr = data + (size_t)(m0 + c16) * (T_STEPS * 32) + 32 + (g4 << 3);
    f32x4 xn0 = *(const f32x4*)(xptr);
    f32x4 xn1 = *(const f32x4*)(xptr + 4);
    f16x8 xfrag = cvt8(xn0, xn1);

    #pragma unroll 1
    for (int s = 0; s < T_STEPS - 1; ++s) {
        const float dt = (s == 0) ? (t1v - t0v) : (ts[s - 1] - ts[s]);

        // ---- slot 1: prefetch next x; G1; xacc3 (G3 x-partials, LDS wts) ----
        xptr += 32;
        if (s < T_STEPS - 2) {
            xn0 = *(const f32x4*)(xptr);
            xn1 = *(const f32x4*)(xptr + 4);
        }
        f32x4 xacc3[4];
        {
            f16x8 b0 = ldsA(sYb, 64, c16, (g4 << 3));
            f16x8 b1 = ldsA(sYb, 64, c16, 32 + (g4 << 3));
            #pragma unroll
            for (int t = 0; t < 2; ++t) {
                int nt = wq + 4 * t;
                if (nt < 7) {
                    f32x4 acc0 = bo1v[t];
                    f32x4 z4 = {0.f, 0.f, 0.f, 0.f};
                    acc0 = MFMA16(Wv[(nt * 2 + 0) * 64 + lane], b0, acc0);
                    f32x4 acc1 = MFMA16(Wv[(nt * 2 + 1) * 64 + lane], b1, z4);
                    int ft = nt * 16 + (g4 << 2);
                    st4(sH1, 128, c16, ft,
                        fast_tanh(acc0[0] + acc1[0]), fast_tanh(acc0[1] + acc1[1]),
                        fast_tanh(acc0[2] + acc1[2]), fast_tanh(acc0[3] + acc1[3]));
                }
            }
            #pragma unroll
            for (int q = 0; q < 4; ++q) {
                int i = wq + 4 * q;
                if (i < 14) xacc3[q] = MFMA16(Wv[(14 + bt3[q] * 3 + 2) * 64 + lane], xfrag, bzrv[q]);
            }
        }
        BAR();

        // ---- slot 2: G2 (yode) + xacc5 (G5 x-partials, LDS wts) ----
        f32x4 xacc5[2];
        {
            f32x4 acc0 = bo2v;
            f32x4 z4 = {0.f, 0.f, 0.f, 0.f};
            acc0 = MFMA16(Ao2[0], ldsA(sH1, 128, c16, 0 * 32 + (g4 << 3)), acc0);
            f32x4 acc1 = MFMA16(Ao2[1], ldsA(sH1, 128, c16, 1 * 32 + (g4 << 3)), z4);
            acc0 = MFMA16(Ao2[2], ldsA(sH1, 128, c16, 2 * 32 + (g4 << 3)), acc0);
            acc1 = MFMA16(Ao2[3], ldsA(sH1, 128, c16, 3 * 32 + (g4 << 3)), acc1);
            #pragma unroll
            for (int t = 0; t < 2; ++t) {
                int nt = wq + 4 * t;
                if (nt < 7)
                    xacc5[t] = MFMA16(Wv[(91 + nt * 3 + 2) * 64 + lane], xfrag, bh1v[t]);
            }
            #pragma unroll
            for (int r = 0; r < 4; ++r) yo[r] = y[r] + dt * (acc0[r] + acc1[r]);
            st4(sYX, 64, c16, f0, yo[0], yo[1], yo[2], yo[3]);
        }
        BAR();

        // ---- slot 3: G3 (2 MFMAs/tile, C-init = x-partial) ----
        {
            f16x8 b0 = ldsA(sYX, 64, c16, (g4 << 3));
            f16x8 b1 = ldsA(sYX, 64, c16, 32 + (g4 << 3));
            #pragma unroll
            for (int q = 0; q < 4; ++q) {
                int i = wq + 4 * q;
                if (i < 14) {
                    f32x4 acc = MFMA16(Wv[(14 + bt3[q] * 3 + 0) * 64 + lane], b0, xacc3[q]);
                    acc = MFMA16(Wv[(14 + bt3[q] * 3 + 1) * 64 + lane], b1, acc);
                    int ft = bt3[q] * 16 + (g4 << 2);
                    st4(sZR, 256, c16, ft,
                        fast_tanh(acc[0]), fast_tanh(acc[1]),
                        fast_tanh(acc[2]), fast_tanh(acc[3]));
                }
            }
        }
        BAR();

        // ---- slot 4: G4 (z-gate -> regs ; r-gate*yode -> sRX) ----
        {
            f32x4 accz0 = bz2v, accr0 = br2v;
            f32x4 z4 = {0.f, 0.f, 0.f, 0.f};
            f32x4 accz1 = z4, accr1 = z4;
            accz0 = MFMA16(Wv[(59 + wq * 4 + 0) * 64 + lane], ldsA(sZR, 256, c16, 0 * 32 + (g4 << 3)), accz0);
            accr0 = MFMA16(Wv[(75 + wq * 4 + 0) * 64 + lane], ldsA(sZR, 256, c16, 128 + 0 * 32 + (g4 << 3)), accr0);
            accz1 = MFMA16(Wv[(59 + wq * 4 + 1) * 64 + lane], ldsA(sZR, 256, c16, 1 * 32 + (g4 << 3)), accz1);
            accr1 = MFMA16(Wv[(75 + wq * 4 + 1) * 64 + lane], ldsA(sZR, 256, c16, 128 + 1 * 32 + (g4 << 3)), accr1);
            accz0 = MFMA16(Wv[(59 + wq * 4 + 2) * 64 + lane], ldsA(sZR, 256, c16, 2 * 32 + (g4 << 3)), accz0);
            accr0 = MFMA16(Wv[(75 + wq * 4 + 2) * 64 + lane], ldsA(sZR, 256, c16, 128 + 2 * 32 + (g4 << 3)), accr0);
            accz1 = MFMA16(Wv[(59 + wq * 4 + 3) * 64 + lane], ldsA(sZR, 256, c16, 3 * 32 + (g4 << 3)), accz1);
            accr1 = MFMA16(Wv[(75 + wq * 4 + 3) * 64 + lane], ldsA(sZR, 256, c16, 128 + 3 * 32 + (g4 << 3)), accr1);
            float rv[4];
            #pragma unroll
            for (int r = 0; r < 4; ++r) {
                zg[r] = fast_sigmoid(accz0[r] + accz1[r]);
                rv[r] = fast_sigmoid(accr0[r] + accr1[r]) * yo[r];
            }
            st4(sRX, 64, c16, f0, rv[0], rv[1], rv[2], rv[3]);
        }
        BAR();

        // ---- slot 5: G5 (2 MFMAs/tile, C-init = x-partial) ----
        {
            f16x8 b0 = ldsA(sRX, 64, c16, (g4 << 3));
            f16x8 b1 = ldsA(sRX, 64, c16, 32 + (g4 << 3));
            #pragma unroll
            for (int t = 0; t < 2; ++t) {
                int nt = wq + 4 * t;
                if (nt < 7) {
                    f32x4 acc = MFMA16(Wv[(91 + nt * 3 + 0) * 64 + lane], b0, xacc5[t]);
                    acc = MFMA16(Wv[(91 + nt * 3 + 1) * 64 + lane], b1, acc);
                    int ft = nt * 16 + (g4 << 2);
                    st4(sH1, 128, c16, ft,
                        fast_tanh(acc[0]), fast_tanh(acc[1]),
                        fast_tanh(acc[2]), fast_tanh(acc[3]));
                }
            }
        }
        BAR();

        // ---- slot 6: G6 (h, blend, y) ----
        {
            f32x4 acc0 = bh2v;
            f32x4 z4 = {0.f, 0.f, 0.f, 0.f};
            acc0 = MFMA16(Ah2[0], ldsA(sH1, 128, c16, 0 * 32 + (g4 << 3)), acc0);
            f32x4 acc1 = MFMA16(Ah2[1], ldsA(sH1, 128, c16, 1 * 32 + (g4 << 3)), z4);
            acc0 = MFMA16(Ah2[2], ldsA(sH1, 128, c16, 2 * 32 + (g4 << 3)), acc0);
            acc1 = MFMA16(Ah2[3], ldsA(sH1, 128, c16, 3 * 32 + (g4 << 3)), acc1);
            #pragma unroll
            for (int r = 0; r < 4; ++r) {
                float h = fast_tanh(acc0[r] + acc1[r]);
                y[r] = (1.f - zg[r]) * h + zg[r] * yo[r];
            }
            st4(sYb, 64, c16, f0, y[0], y[1], y[2], y[3]);
        }
        BAR();

        xfrag = cvt8(xn0, xn1);   // pack prefetched x for next step
    }

    {
        f32x4 ov = {y[0], y[1], y[2], y[3]};
        *(f32x4*)(out + (size_t)(m0 + c16) * 64 + f0) = ov;
    }
}

extern "C" void kernel_launch(void* const* d_in, const int* in_sizes, int n_in,
                              void* d_out, int out_size, void* d_ws, size_t ws_size,
                              hipStream_t stream) {
    const float* data = (const float*)d_in[0];
    const float* ts   = (const float*)d_in[1];
    const float* prior= (const float*)d_in[2];
    const float* Wo1 = (const float*)d_in[3];  const float* bo1 = (const float*)d_in[4];
    const float* Wo2 = (const float*)d_in[5];  const float* bo2 = (const float*)d_in[6];
    const float* Wz1 = (const float*)d_in[7];  const float* bz1 = (const float*)d_in[8];
    const float* Wz2 = (const float*)d_in[9];  const float* bz2 = (const float*)d_in[10];
    const float* Wr1 = (const float*)d_in[11]; const float* br1 = (const float*)d_in[12];
    const float* Wr2 = (const float*)d_in[13]; const float* br2 = (const float*)d_in[14];
    const float* Wh1 = (const float*)d_in[15]; const float* bh1 = (const float*)d_in[16];
    const float* Wh2 = (const float*)d_in[17]; const float* bh2 = (const float*)d_in[18];
    _Float16* P = (_Float16*)d_ws;
    float* out = (float*)d_out;

    (void)hipFuncSetAttribute((const void*)odernn_kernel,
                              hipFuncAttributeMaxDynamicSharedMemorySize, LDS_TOTAL);

    hipLaunchKernelGGL(pack_kernel, dim3((144 * 512 + 255) / 256), dim3(256), 0, stream,
                       Wo1, Wo2, Wz1, Wz2, Wr1, Wr2, Wh1, Wh2, P);
    hipLaunchKernelGGL(odernn_kernel, dim3(NTRAJ / MBLK), dim3(512), LDS_TOTAL, stream,
                       data, ts, prior, bo1, bo2, bz1, bz2, br1, br2, bh1, bh2, P, out);
}

// Round 17
// 285.373 us; speedup vs baseline: 1.3290x; 1.2803x over previous
//
#include <hip/hip_runtime.h>

#define T_STEPS 100
#define NTRAJ   8192
#define MBLK    32     // two 16-row tile groups per block
#define W_TILES 112
#define W_BYTES (W_TILES * 1024)            // 114688: G1/G3/G4/G5 weights in LDS
#define TILEBUF 18432                       // per-group activation buffers
#define LDS_TOTAL (W_BYTES + 2 * TILEBUF)   // 151552 <= 163840

typedef __attribute__((ext_vector_type(8))) _Float16 f16x8;
typedef __attribute__((ext_vector_type(4))) _Float16 f16x4;
typedef __attribute__((ext_vector_type(2))) __fp16   h16x2;   // cvt_pkrtz return type
typedef __attribute__((ext_vector_type(4))) float    f32x4;

#define MFMA16(a, b, c) __builtin_amdgcn_mfma_f32_16x16x32_f16((a), (b), (c), 0, 0, 0)

// XOR swizzle on element index within a row (2B elems; XOR elem bits 3..5)
#define SWZ(row, col) ((col) ^ (((row) & 7) << 3))

// R15 lesson: lgkmcnt-only asm barriers and exp2f both REGRESS (-22% total).
// Plain __syncthreads() + __expf (native v_exp path) restored.
__device__ __forceinline__ float fast_tanh(float x) {
    float e = __expf(2.f * x);
    return 1.f - 2.f * __builtin_amdgcn_rcpf(1.f + e);
}
__device__ __forceinline__ float fast_sigmoid(float x) {
    float e = __expf(-x);
    return __builtin_amdgcn_rcpf(1.f + e);
}

// ---------------------------------------------------------------------------
// Weight packing (UNCHANGED): tile = 512 f16, element (lane, j) = W[k][n],
// k = kt*32 + (lane>>4)*8 + j, n = nt*16 + (lane&15). A-operand of W^T.
//   [0,14) G1 | [14,30) G2 | [30,75) G3 | [75,107) G4 | [107,128) G5 | [128,144) G6
// ---------------------------------------------------------------------------
__global__ void pack_kernel(const float* __restrict__ Wo1, const float* __restrict__ Wo2,
                            const float* __restrict__ Wz1, const float* __restrict__ Wz2,
                            const float* __restrict__ Wr1, const float* __restrict__ Wr2,
                            const float* __restrict__ Wh1, const float* __restrict__ Wh2,
                            _Float16* __restrict__ P)
{
    int idx = blockIdx.x * 256 + threadIdx.x;
    if (idx >= 144 * 512) return;
    int tile = idx >> 9;
    int r    = idx & 511;
    int lane = r >> 3, j = r & 7;
    int krel = ((lane >> 4) << 3) + j;   // 0..31
    int c16  = lane & 15;
    float val = 0.f;

    if (tile < 14) {                       // ODE L1
        int t = tile, nt = t >> 1, kt = t & 1;
        int k = kt * 32 + krel, n = nt * 16 + c16;
        if (k < 64 && n < 100) val = Wo1[k * 100 + n];
    } else if (tile < 30) {                // ODE L2
        int t = tile - 14, nt = t >> 2, kt = t & 3;
        int k = kt * 32 + krel, n = nt * 16 + c16;
        if (k < 100) val = Wo2[k * 64 + n];
    } else if (tile < 75) {                // ZR L1
        int t = tile - 30, nt = t / 3, kt = t % 3;
        int k = kt * 32 + krel;            // K = 96 exact
        if (nt < 7)      { int n = nt * 16 + c16;        if (n < 100) val = Wz1[k * 100 + n]; }
        else if (nt >= 8){ int n = (nt - 8) * 16 + c16;  if (n < 100) val = Wr1[k * 100 + n]; }
    } else if (tile < 107) {               // ZR L2
        int t = tile - 75, gate = t >> 4, rem = t & 15, nt = rem >> 2, kt = rem & 3;
        int k = kt * 32 + krel, n = nt * 16 + c16;
        const float* W = gate ? Wr2 : Wz2;
        if (k < 100) val = W[k * 64 + n];
    } else if (tile < 128) {               // H L1
        int t = tile - 107, nt = t / 3, kt = t % 3;
        int k = kt * 32 + krel, n = nt * 16 + c16;
        if (n < 100) val = Wh1[k * 100 + n];
    } else {                               // H L2
        int t = tile - 128, nt = t >> 2, kt = t & 3;
        int k = kt * 32 + krel, n = nt * 16 + c16;
        if (k < 100) val = Wh2[k * 64 + n];
    }
    P[idx] = (_Float16)val;
}

// activation B-fragment read: n = traj = lane&15, k-slice contiguous 8
__device__ __forceinline__ f16x8 ldsA(const _Float16* buf, int stride, int row, int kcol) {
    return *(const f16x8*)(buf + row * stride + SWZ(row, kcol));
}
// contiguous 4-feature epilogue store (one b64)
__device__ __forceinline__ void st4(_Float16* buf, int stride, int traj, int f0,
                                    float a, float b, float c, float d) {
    f16x4 h = {(_Float16)a, (_Float16)b, (_Float16)c, (_Float16)d};
    *(f16x4*)(buf + traj * stride + SWZ(traj, f0)) = h;
}
__device__ __forceinline__ f32x4 loadBias4(const float* b, int f0, int n) {
    f32x4 v = {0.f, 0.f, 0.f, 0.f};
    #pragma unroll
    for (int r = 0; r < 4; ++r) if (f0 + r < n) v[r] = b[f0 + r];
    return v;
}
// pack 8 f32 (two f32x4) -> f16x8 via cvt_pkrtz
__device__ __forceinline__ f16x8 cvt8(f32x4 a, f32x4 b) {
    union { h16x2 h2[4]; f16x8 v; } u;
    u.h2[0] = __builtin_amdgcn_cvt_pkrtz(a[0], a[1]);
    u.h2[1] = __builtin_amdgcn_cvt_pkrtz(a[2], a[3]);
    u.h2[2] = __builtin_amdgcn_cvt_pkrtz(b[0], b[1]);
    u.h2[3] = __builtin_amdgcn_cvt_pkrtz(b[2], b[3]);
    return u.v;
}

// ---------------------------------------------------------------------------
// R11 structure (verified 299us best) + ONE bounded change: G4's 8 weight
// fragments (Wg4z/Wg4r, 32 VGPR) preloaded to registers, filling exactly the
// 96->128 arch-VGPR headroom. Removes 8 of slot-4's 16 ds_read_b128 (its
// deepest latency chain) and 1/3 of per-step weight LDS traffic.
// __syncthreads + __expf restored (R15: BAR/exp2f regress 22%).
// ---------------------------------------------------------------------------
__global__ __launch_bounds__(512, 2) void odernn_kernel(
    const float* __restrict__ data, const float* __restrict__ ts,
    const float* __restrict__ prior,
    const float* __restrict__ bo1, const float* __restrict__ bo2,
    const float* __restrict__ bz1, const float* __restrict__ bz2,
    const float* __restrict__ br1, const float* __restrict__ br2,
    const float* __restrict__ bh1, const float* __restrict__ bh2,
    const _Float16* __restrict__ P, float* __restrict__ out)
{
    extern __shared__ __align__(16) char smem[];
    _Float16* W = (_Float16*)smem;        // 112 tiles: G1[0,14) G3[14,59) G4[59,91) G5[91,112)

    const int tid  = threadIdx.x;
    const int lane = tid & 63;
    const int wv   = tid >> 6;            // 0..7
    const int tg   = wv >> 2;             // tile group 0/1
    const int wq   = wv & 3;              // wave-in-group
    const int c16  = lane & 15;           // trajectory within group
    const int g4   = lane >> 4;
    const int m0   = blockIdx.x * MBLK + tg * 16;
    const int f0   = wq * 16 + (g4 << 2); // lane's own 4-feature base (tile nt=wq)
    const f16x8* Pt = (const f16x8*)P;
    const f16x8* Wv = (const f16x8*)W;

    _Float16* base = (_Float16*)(smem + W_BYTES + tg * TILEBUF);
    _Float16* sYb = base;                 // [16][64]  y
    _Float16* sYX = base + 1024;          // [16][64]  yode
    _Float16* sRX = base + 2048;          // [16][64]  rg*yode
    _Float16* sH1 = base + 3072;          // [16][128] hidden
    _Float16* sZR = base + 5120;          // [16][256] [zh|rh] + pads

    // ---- stage G1/G3/G4/G5 weights into LDS ----
    {
        f16x8* Wd = (f16x8*)W;
        #pragma unroll
        for (int it = 0; it < 14; ++it) {
            int idx = tid + it * 512;
            int ldst = idx >> 6, l = idx & 63;
            int srct = (ldst < 14) ? ldst : ldst + 16;   // skip G2 range
            Wd[idx] = Pt[srct * 64 + l];
        }
    }

    // ---- G3/G5 tile indices for this wave ----
    int bt3[4];
    #pragma unroll
    for (int q = 0; q < 4; ++q) {
        int i = wq + 4 * q;
        bt3[q] = (i < 14) ? ((i < 7) ? i : i + 1) : 0;
    }

    // ---- biases as per-lane f32x4 feature vectors ----
    f32x4 bo1v[2], bh1v[2], bzrv[4];
    #pragma unroll
    for (int t = 0; t < 2; ++t) {
        int nt = wq + 4 * t;
        f32x4 zo = {0.f,0.f,0.f,0.f};
        if (nt < 7) {
            int ft = nt * 16 + (g4 << 2);
            bo1v[t] = loadBias4(bo1, ft, 100);
            bh1v[t] = loadBias4(bh1, ft, 100);
        } else { bo1v[t] = zo; bh1v[t] = zo; }
    }
    #pragma unroll
    for (int q = 0; q < 4; ++q) {
        int i = wq + 4 * q;
        f32x4 v = {0.f,0.f,0.f,0.f};
        if (i < 14) {
            int ft = bt3[q] * 16 + (g4 << 2);
            if (i < 7) v = loadBias4(bz1, ft, 100);
            else       v = loadBias4(br1, ft - 128, 100);
        }
        bzrv[q] = v;
    }
    const f32x4 bo2v = *(const f32x4*)(bo2 + f0);
    const f32x4 bz2v = *(const f32x4*)(bz2 + f0);
    const f32x4 br2v = *(const f32x4*)(br2 + f0);
    const f32x4 bh2v = *(const f32x4*)(bh2 + f0);

    // ---- register A-frags: G2/G6 (as R11) + G4 z/r (new, fills 96->128) ----
    f16x8 Ao2[4], Ah2[4], Wg4z[4], Wg4r[4];
    #pragma unroll
    for (int kt = 0; kt < 4; ++kt) {
        Ao2[kt]  = Pt[(14 + wq * 4 + kt) * 64 + lane];
        Ah2[kt]  = Pt[(128 + wq * 4 + kt) * 64 + lane];
        Wg4z[kt] = Pt[(75 + wq * 4 + kt) * 64 + lane];
        Wg4r[kt] = Pt[(91 + wq * 4 + kt) * 64 + lane];
    }

    // ---- init state ----
    float y[4], yo[4] = {0,0,0,0}, zg[4] = {0,0,0,0};
    {
        f32x4 pv = *(const f32x4*)(prior + (size_t)(m0 + c16) * 64 + f0);
        #pragma unroll
        for (int r = 0; r < 4; ++r) y[r] = pv[r];
        st4(sYb, 64, c16, f0, y[0], y[1], y[2], y[3]);
    }
    {   // sH1 pad feats 112..127, both groups (512 elems, 1/thread)
        int row32 = tid >> 4, col = 112 + (tid & 15);
        int t = row32 >> 4, r16 = row32 & 15;
        _Float16* h1 = (_Float16*)(smem + W_BYTES + t * TILEBUF) + 3072;
        h1[r16 * 128 + SWZ(r16, col)] = (_Float16)0.f;
    }
    for (int i = tid; i < 2 * 16 * 32; i += 512) {   // sZR pads, both groups
        int t = i >> 9, rem = i & 511;
        int r16 = rem >> 5, cc = rem & 31;
        int col = (cc < 16) ? (112 + cc) : (224 + cc);
        _Float16* zr = (_Float16*)(smem + W_BYTES + t * TILEBUF) + 5120;
        zr[r16 * 256 + SWZ(r16, col)] = (_Float16)0.f;
    }
    __syncthreads();

    const float t0v = ts[0], t1v = ts[1];

    // ---- x fragment: lane owns x[traj=c16][feat g4*8 .. g4*8+7] ----
    const float* xptr = data + (size_t)(m0 + c16) * (T_STEPS * 32) + 32 + (g4 << 3);
    f32x4 xn0 = *(const f32x4*)(xptr);
    f32x4 xn1 = *(const f32x4*)(xptr + 4);
    f16x8 xfrag = cvt8(xn0, xn1);

    #pragma unroll 1
    for (int s = 0; s < T_STEPS - 1; ++s) {
        const float dt = (s == 0) ? (t1v - t0v) : (ts[s - 1] - ts[s]);

        // ---- slot 1: prefetch next x; G1; xacc3 (G3 x-partials) ----
        xptr += 32;
        if (s < T_STEPS - 2) {
            xn0 = *(const f32x4*)(xptr);
            xn1 = *(const f32x4*)(xptr + 4);
        }
        f32x4 xacc3[4];
        {
            f16x8 b0 = ldsA(sYb, 64, c16, (g4 << 3));
            f16x8 b1 = ldsA(sYb, 64, c16, 32 + (g4 << 3));
            #pragma unroll
            for (int t = 0; t < 2; ++t) {
                int nt = wq + 4 * t;
                if (nt < 7) {
                    f32x4 acc0 = bo1v[t];
                    f32x4 z4 = {0.f, 0.f, 0.f, 0.f};
                    acc0 = MFMA16(Wv[(nt * 2 + 0) * 64 + lane], b0, acc0);
                    f32x4 acc1 = MFMA16(Wv[(nt * 2 + 1) * 64 + lane], b1, z4);
                    int ft = nt * 16 + (g4 << 2);
                    st4(sH1, 128, c16, ft,
                        fast_tanh(acc0[0] + acc1[0]), fast_tanh(acc0[1] + acc1[1]),
                        fast_tanh(acc0[2] + acc1[2]), fast_tanh(acc0[3] + acc1[3]));
                }
            }
            #pragma unroll
            for (int q = 0; q < 4; ++q) {
                int i = wq + 4 * q;
                if (i < 14) xacc3[q] = MFMA16(Wv[(14 + bt3[q] * 3 + 2) * 64 + lane], xfrag, bzrv[q]);
            }
        }
        __syncthreads();

        // ---- slot 2: G2 (yode) + xacc5 (G5 x-partials) ----
        f32x4 xacc5[2];
        {
            f32x4 acc0 = bo2v;
            f32x4 z4 = {0.f, 0.f, 0.f, 0.f};
            acc0 = MFMA16(Ao2[0], ldsA(sH1, 128, c16, 0 * 32 + (g4 << 3)), acc0);
            f32x4 acc1 = MFMA16(Ao2[1], ldsA(sH1, 128, c16, 1 * 32 + (g4 << 3)), z4);
            acc0 = MFMA16(Ao2[2], ldsA(sH1, 128, c16, 2 * 32 + (g4 << 3)), acc0);
            acc1 = MFMA16(Ao2[3], ldsA(sH1, 128, c16, 3 * 32 + (g4 << 3)), acc1);
            #pragma unroll
            for (int t = 0; t < 2; ++t) {
                int nt = wq + 4 * t;
                if (nt < 7)
                    xacc5[t] = MFMA16(Wv[(91 + nt * 3 + 2) * 64 + lane], xfrag, bh1v[t]);
            }
            #pragma unroll
            for (int r = 0; r < 4; ++r) yo[r] = y[r] + dt * (acc0[r] + acc1[r]);
            st4(sYX, 64, c16, f0, yo[0], yo[1], yo[2], yo[3]);
        }
        __syncthreads();

        // ---- slot 3: G3 (2 MFMAs/tile, C-init = x-partial) ----
        {
            f16x8 b0 = ldsA(sYX, 64, c16, (g4 << 3));
            f16x8 b1 = ldsA(sYX, 64, c16, 32 + (g4 << 3));
            #pragma unroll
            for (int q = 0; q < 4; ++q) {
                int i = wq + 4 * q;
                if (i < 14) {
                    f32x4 acc = MFMA16(Wv[(14 + bt3[q] * 3 + 0) * 64 + lane], b0, xacc3[q]);
                    acc = MFMA16(Wv[(14 + bt3[q] * 3 + 1) * 64 + lane], b1, acc);
                    int ft = bt3[q] * 16 + (g4 << 2);
                    st4(sZR, 256, c16, ft,
                        fast_tanh(acc[0]), fast_tanh(acc[1]),
                        fast_tanh(acc[2]), fast_tanh(acc[3]));
                }
            }
        }
        __syncthreads();

        // ---- slot 4: G4 (REGISTER weights; z-gate -> regs, r-gate*yode -> sRX) ----
        {
            f32x4 accz0 = bz2v, accr0 = br2v;
            f32x4 z4 = {0.f, 0.f, 0.f, 0.f};
            f32x4 accz1 = z4, accr1 = z4;
            accz0 = MFMA16(Wg4z[0], ldsA(sZR, 256, c16, 0 * 32 + (g4 << 3)), accz0);
            accr0 = MFMA16(Wg4r[0], ldsA(sZR, 256, c16, 128 + 0 * 32 + (g4 << 3)), accr0);
            accz1 = MFMA16(Wg4z[1], ldsA(sZR, 256, c16, 1 * 32 + (g4 << 3)), accz1);
            accr1 = MFMA16(Wg4r[1], ldsA(sZR, 256, c16, 128 + 1 * 32 + (g4 << 3)), accr1);
            accz0 = MFMA16(Wg4z[2], ldsA(sZR, 256, c16, 2 * 32 + (g4 << 3)), accz0);
            accr0 = MFMA16(Wg4r[2], ldsA(sZR, 256, c16, 128 + 2 * 32 + (g4 << 3)), accr0);
            accz1 = MFMA16(Wg4z[3], ldsA(sZR, 256, c16, 3 * 32 + (g4 << 3)), accz1);
            accr1 = MFMA16(Wg4r[3], ldsA(sZR, 256, c16, 128 + 3 * 32 + (g4 << 3)), accr1);
            float rv[4];
            #pragma unroll
            for (int r = 0; r < 4; ++r) {
                zg[r] = fast_sigmoid(accz0[r] + accz1[r]);
                rv[r] = fast_sigmoid(accr0[r] + accr1[r]) * yo[r];
            }
            st4(sRX, 64, c16, f0, rv[0], rv[1], rv[2], rv[3]);
        }
        __syncthreads();

        // ---- slot 5: G5 (2 MFMAs/tile, C-init = x-partial) ----
        {
            f16x8 b0 = ldsA(sRX, 64, c16, (g4 << 3));
            f16x8 b1 = ldsA(sRX, 64, c16, 32 + (g4 << 3));
            #pragma unroll
            for (int t = 0; t < 2; ++t) {
                int nt = wq + 4 * t;
                if (nt < 7) {
                    f32x4 acc = MFMA16(Wv[(91 + nt * 3 + 0) * 64 + lane], b0, xacc5[t]);
                    acc = MFMA16(Wv[(91 + nt * 3 + 1) * 64 + lane], b1, acc);
                    int ft = nt * 16 + (g4 << 2);
                    st4(sH1, 128, c16, ft,
                        fast_tanh(acc[0]), fast_tanh(acc[1]),
                        fast_tanh(acc[2]), fast_tanh(acc[3]));
                }
            }
        }
        __syncthreads();

        // ---- slot 6: G6 (h, blend, y) ----
        {
            f32x4 acc0 = bh2v;
            f32x4 z4 = {0.f, 0.f, 0.f, 0.f};
            acc0 = MFMA16(Ah2[0], ldsA(sH1, 128, c16, 0 * 32 + (g4 << 3)), acc0);
            f32x4 acc1 = MFMA16(Ah2[1], ldsA(sH1, 128, c16, 1 * 32 + (g4 << 3)), z4);
            acc0 = MFMA16(Ah2[2], ldsA(sH1, 128, c16, 2 * 32 + (g4 << 3)), acc0);
            acc1 = MFMA16(Ah2[3], ldsA(sH1, 128, c16, 3 * 32 + (g4 << 3)), acc1);
            #pragma unroll
            for (int r = 0; r < 4; ++r) {
                float h = fast_tanh(acc0[r] + acc1[r]);
                y[r] = (1.f - zg[r]) * h + zg[r] * yo[r];
            }
            st4(sYb, 64, c16, f0, y[0], y[1], y[2], y[3]);
        }
        __syncthreads();

        xfrag = cvt8(xn0, xn1);   // pack prefetched x for next step
    }

    {
        f32x4 ov = {y[0], y[1], y[2], y[3]};
        *(f32x4*)(out + (size_t)(m0 + c16) * 64 + f0) = ov;
    }
}

extern "C" void kernel_launch(void* const* d_in, const int* in_sizes, int n_in,
                              void* d_out, int out_size, void* d_ws, size_t ws_size,
                              hipStream_t stream) {
    const float* data = (const float*)d_in[0];
    const float* ts   = (const float*)d_in[1];
    const float* prior= (const float*)d_in[2];
    const float* Wo1 = (const float*)d_in[3];  const float* bo1 = (const float*)d_in[4];
    const float* Wo2 = (const float*)d_in[5];  const float* bo2 = (const float*)d_in[6];
    const float* Wz1 = (const float*)d_in[7];  const float* bz1 = (const float*)d_in[8];
    const float* Wz2 = (const float*)d_in[9];  const float* bz2 = (const float*)d_in[10];
    const float* Wr1 = (const float*)d_in[11]; const float* br1 = (const float*)d_in[12];
    const float* Wr2 = (const float*)d_in[13]; const float* br2 = (const float*)d_in[14];
    const float* Wh1 = (const float*)d_in[15]; const float* bh1 = (const float*)d_in[16];
    const float* Wh2 = (const float*)d_in[17]; const float* bh2 = (const float*)d_in[18];
    _Float16* P = (_Float16*)d_ws;
    float* out = (float*)d_out;

    (void)hipFuncSetAttribute((const void*)odernn_kernel,
                              hipFuncAttributeMaxDynamicSharedMemorySize, LDS_TOTAL);

    hipLaunchKernelGGL(pack_kernel, dim3((144 * 512 + 255) / 256), dim3(256), 0, stream,
                       Wo1, Wo2, Wz1, Wz2, Wr1, Wr2, Wh1, Wh2, P);
    hipLaunchKernelGGL(odernn_kernel, dim3(NTRAJ / MBLK), dim3(512), LDS_TOTAL, stream,
                       data, ts, prior, bo1, bo2, bz1, bz2, br1, br2, bh1, bh2, P, out);
}

// Round 18
// 279.621 us; speedup vs baseline: 1.3563x; 1.0206x over previous
//
#include <hip/hip_runtime.h>

#define T_STEPS 100
#define NTRAJ   8192
#define MBLK    32     // two 16-row tile groups per block
#define W_TILES 112
#define W_BYTES (W_TILES * 1024)            // 114688: G1/G3/G4/G5 weights in LDS
#define TILEBUF 18432                       // per-group activation buffers
#define LDS_TOTAL (W_BYTES + 2 * TILEBUF)   // 151552 <= 163840

typedef __attribute__((ext_vector_type(8))) _Float16 f16x8;
typedef __attribute__((ext_vector_type(4))) _Float16 f16x4;
typedef __attribute__((ext_vector_type(2))) __fp16   h16x2;   // cvt_pkrtz return type
typedef __attribute__((ext_vector_type(4))) float    f32x4;

#define MFMA16(a, b, c) __builtin_amdgcn_mfma_f32_16x16x32_f16((a), (b), (c), 0, 0, 0)

// XOR swizzle on element index within a row (2B elems; XOR elem bits 3..5)
#define SWZ(row, col) ((col) ^ (((row) & 7) << 3))

// __syncthreads + __expf (R15: asm barriers / exp2f regress 22%)
__device__ __forceinline__ float fast_tanh(float x) {
    float e = __expf(2.f * x);
    return 1.f - 2.f * __builtin_amdgcn_rcpf(1.f + e);
}
__device__ __forceinline__ float fast_sigmoid(float x) {
    float e = __expf(-x);
    return __builtin_amdgcn_rcpf(1.f + e);
}

// ---------------------------------------------------------------------------
// Weight packing (UNCHANGED): tile = 512 f16, element (lane, j) = W[k][n],
// k = kt*32 + (lane>>4)*8 + j, n = nt*16 + (lane&15). A-operand of W^T.
//   [0,14) G1 | [14,30) G2 | [30,75) G3 | [75,107) G4 | [107,128) G5 | [128,144) G6
// ---------------------------------------------------------------------------
__global__ void pack_kernel(const float* __restrict__ Wo1, const float* __restrict__ Wo2,
                            const float* __restrict__ Wz1, const float* __restrict__ Wz2,
                            const float* __restrict__ Wr1, const float* __restrict__ Wr2,
                            const float* __restrict__ Wh1, const float* __restrict__ Wh2,
                            _Float16* __restrict__ P)
{
    int idx = blockIdx.x * 256 + threadIdx.x;
    if (idx >= 144 * 512) return;
    int tile = idx >> 9;
    int r    = idx & 511;
    int lane = r >> 3, j = r & 7;
    int krel = ((lane >> 4) << 3) + j;   // 0..31
    int c16  = lane & 15;
    float val = 0.f;

    if (tile < 14) {                       // ODE L1
        int t = tile, nt = t >> 1, kt = t & 1;
        int k = kt * 32 + krel, n = nt * 16 + c16;
        if (k < 64 && n < 100) val = Wo1[k * 100 + n];
    } else if (tile < 30) {                // ODE L2
        int t = tile - 14, nt = t >> 2, kt = t & 3;
        int k = kt * 32 + krel, n = nt * 16 + c16;
        if (k < 100) val = Wo2[k * 64 + n];
    } else if (tile < 75) {                // ZR L1
        int t = tile - 30, nt = t / 3, kt = t % 3;
        int k = kt * 32 + krel;            // K = 96 exact
        if (nt < 7)      { int n = nt * 16 + c16;        if (n < 100) val = Wz1[k * 100 + n]; }
        else if (nt >= 8){ int n = (nt - 8) * 16 + c16;  if (n < 100) val = Wr1[k * 100 + n]; }
    } else if (tile < 107) {               // ZR L2
        int t = tile - 75, gate = t >> 4, rem = t & 15, nt = rem >> 2, kt = rem & 3;
        int k = kt * 32 + krel, n = nt * 16 + c16;
        const float* W = gate ? Wr2 : Wz2;
        if (k < 100) val = W[k * 64 + n];
    } else if (tile < 128) {               // H L1
        int t = tile - 107, nt = t / 3, kt = t % 3;
        int k = kt * 32 + krel, n = nt * 16 + c16;
        if (n < 100) val = Wh1[k * 100 + n];
    } else {                               // H L2
        int t = tile - 128, nt = t >> 2, kt = t & 3;
        int k = kt * 32 + krel, n = nt * 16 + c16;
        if (k < 100) val = Wh2[k * 64 + n];
    }
    P[idx] = (_Float16)val;
}

// activation B-fragment read: n = traj = lane&15, k-slice contiguous 8
__device__ __forceinline__ f16x8 ldsA(const _Float16* buf, int stride, int row, int kcol) {
    return *(const f16x8*)(buf + row * stride + SWZ(row, kcol));
}
// contiguous 4-feature epilogue store (one b64)
__device__ __forceinline__ void st4(_Float16* buf, int stride, int traj, int f0,
                                    float a, float b, float c, float d) {
    f16x4 h = {(_Float16)a, (_Float16)b, (_Float16)c, (_Float16)d};
    *(f16x4*)(buf + traj * stride + SWZ(traj, f0)) = h;
}
__device__ __forceinline__ f32x4 loadBias4(const float* b, int f0, int n) {
    f32x4 v = {0.f, 0.f, 0.f, 0.f};
    #pragma unroll
    for (int r = 0; r < 4; ++r) if (f0 + r < n) v[r] = b[f0 + r];
    return v;
}
// pack 8 f32 (two f32x4) -> f16x8 via cvt_pkrtz
__device__ __forceinline__ f16x8 cvt8(f32x4 a, f32x4 b) {
    union { h16x2 h2[4]; f16x8 v; } u;
    u.h2[0] = __builtin_amdgcn_cvt_pkrtz(a[0], a[1]);
    u.h2[1] = __builtin_amdgcn_cvt_pkrtz(a[2], a[3]);
    u.h2[2] = __builtin_amdgcn_cvt_pkrtz(b[0], b[1]);
    u.h2[3] = __builtin_amdgcn_cvt_pkrtz(b[2], b[3]);
    return u.v;
}

// ---------------------------------------------------------------------------
// R16 (verified 285us best) + the same bounded lever again: Wg1 (4 frags)
// and Wx5 (2 frags) -> registers, using the 104->128 arch-VGPR headroom.
// Removes 4 of slot-1's and 2 of slot-2's weight ds_reads (22 -> 16/step).
// Each frag moved LDS->reg has paid ~1.5-2us (R16 evidence).
// ---------------------------------------------------------------------------
__global__ __launch_bounds__(512, 2) void odernn_kernel(
    const float* __restrict__ data, const float* __restrict__ ts,
    const float* __restrict__ prior,
    const float* __restrict__ bo1, const float* __restrict__ bo2,
    const float* __restrict__ bz1, const float* __restrict__ bz2,
    const float* __restrict__ br1, const float* __restrict__ br2,
    const float* __restrict__ bh1, const float* __restrict__ bh2,
    const _Float16* __restrict__ P, float* __restrict__ out)
{
    extern __shared__ __align__(16) char smem[];
    _Float16* W = (_Float16*)smem;        // 112 tiles: G1[0,14) G3[14,59) G4[59,91) G5[91,112)

    const int tid  = threadIdx.x;
    const int lane = tid & 63;
    const int wv   = tid >> 6;            // 0..7
    const int tg   = wv >> 2;             // tile group 0/1
    const int wq   = wv & 3;              // wave-in-group
    const int c16  = lane & 15;           // trajectory within group
    const int g4   = lane >> 4;
    const int m0   = blockIdx.x * MBLK + tg * 16;
    const int f0   = wq * 16 + (g4 << 2); // lane's own 4-feature base (tile nt=wq)
    const f16x8* Pt = (const f16x8*)P;
    const f16x8* Wv = (const f16x8*)W;

    _Float16* base = (_Float16*)(smem + W_BYTES + tg * TILEBUF);
    _Float16* sYb = base;                 // [16][64]  y
    _Float16* sYX = base + 1024;          // [16][64]  yode
    _Float16* sRX = base + 2048;          // [16][64]  rg*yode
    _Float16* sH1 = base + 3072;          // [16][128] hidden
    _Float16* sZR = base + 5120;          // [16][256] [zh|rh] + pads

    // ---- stage G1/G3/G4/G5 weights into LDS ----
    {
        f16x8* Wd = (f16x8*)W;
        #pragma unroll
        for (int it = 0; it < 14; ++it) {
            int idx = tid + it * 512;
            int ldst = idx >> 6, l = idx & 63;
            int srct = (ldst < 14) ? ldst : ldst + 16;   // skip G2 range
            Wd[idx] = Pt[srct * 64 + l];
        }
    }

    // ---- G3/G5 tile indices for this wave ----
    int bt3[4];
    #pragma unroll
    for (int q = 0; q < 4; ++q) {
        int i = wq + 4 * q;
        bt3[q] = (i < 14) ? ((i < 7) ? i : i + 1) : 0;
    }
    const int nt1a = wq, nt1b = (wq + 4 < 7) ? wq + 4 : 6;   // G1/G5 tile ids

    // ---- biases as per-lane f32x4 feature vectors ----
    f32x4 bo1v[2], bh1v[2], bzrv[4];
    #pragma unroll
    for (int t = 0; t < 2; ++t) {
        int nt = wq + 4 * t;
        f32x4 zo = {0.f,0.f,0.f,0.f};
        if (nt < 7) {
            int ft = nt * 16 + (g4 << 2);
            bo1v[t] = loadBias4(bo1, ft, 100);
            bh1v[t] = loadBias4(bh1, ft, 100);
        } else { bo1v[t] = zo; bh1v[t] = zo; }
    }
    #pragma unroll
    for (int q = 0; q < 4; ++q) {
        int i = wq + 4 * q;
        f32x4 v = {0.f,0.f,0.f,0.f};
        if (i < 14) {
            int ft = bt3[q] * 16 + (g4 << 2);
            if (i < 7) v = loadBias4(bz1, ft, 100);
            else       v = loadBias4(br1, ft - 128, 100);
        }
        bzrv[q] = v;
    }
    const f32x4 bo2v = *(const f32x4*)(bo2 + f0);
    const f32x4 bz2v = *(const f32x4*)(bz2 + f0);
    const f32x4 br2v = *(const f32x4*)(br2 + f0);
    const f32x4 bh2v = *(const f32x4*)(bh2 + f0);

    // ---- register A-frags: G2/G6/G4 (R16) + G1 and G5-x (new, fills to ~128) ----
    f16x8 Ao2[4], Ah2[4], Wg4z[4], Wg4r[4], Wg1[2][2], Wx5[2];
    #pragma unroll
    for (int kt = 0; kt < 4; ++kt) {
        Ao2[kt]  = Pt[(14 + wq * 4 + kt) * 64 + lane];
        Ah2[kt]  = Pt[(128 + wq * 4 + kt) * 64 + lane];
        Wg4z[kt] = Pt[(75 + wq * 4 + kt) * 64 + lane];
        Wg4r[kt] = Pt[(91 + wq * 4 + kt) * 64 + lane];
    }
    #pragma unroll
    for (int kt = 0; kt < 2; ++kt) {
        Wg1[0][kt] = Pt[(nt1a * 2 + kt) * 64 + lane];
        Wg1[1][kt] = Pt[(nt1b * 2 + kt) * 64 + lane];
    }
    Wx5[0] = Pt[(107 + nt1a * 3 + 2) * 64 + lane];
    Wx5[1] = Pt[(107 + nt1b * 3 + 2) * 64 + lane];

    // ---- init state ----
    float y[4], yo[4] = {0,0,0,0}, zg[4] = {0,0,0,0};
    {
        f32x4 pv = *(const f32x4*)(prior + (size_t)(m0 + c16) * 64 + f0);
        #pragma unroll
        for (int r = 0; r < 4; ++r) y[r] = pv[r];
        st4(sYb, 64, c16, f0, y[0], y[1], y[2], y[3]);
    }
    {   // sH1 pad feats 112..127, both groups (512 elems, 1/thread)
        int row32 = tid >> 4, col = 112 + (tid & 15);
        int t = row32 >> 4, r16 = row32 & 15;
        _Float16* h1 = (_Float16*)(smem + W_BYTES + t * TILEBUF) + 3072;
        h1[r16 * 128 + SWZ(r16, col)] = (_Float16)0.f;
    }
    for (int i = tid; i < 2 * 16 * 32; i += 512) {   // sZR pads, both groups
        int t = i >> 9, rem = i & 511;
        int r16 = rem >> 5, cc = rem & 31;
        int col = (cc < 16) ? (112 + cc) : (224 + cc);
        _Float16* zr = (_Float16*)(smem + W_BYTES + t * TILEBUF) + 5120;
        zr[r16 * 256 + SWZ(r16, col)] = (_Float16)0.f;
    }
    __syncthreads();

    const float t0v = ts[0], t1v = ts[1];

    // ---- x fragment: lane owns x[traj=c16][feat g4*8 .. g4*8+7] ----
    const float* xptr = data + (size_t)(m0 + c16) * (T_STEPS * 32) + 32 + (g4 << 3);
    f32x4 xn0 = *(const f32x4*)(xptr);
    f32x4 xn1 = *(const f32x4*)(xptr + 4);
    f16x8 xfrag = cvt8(xn0, xn1);

    #pragma unroll 1
    for (int s = 0; s < T_STEPS - 1; ++s) {
        const float dt = (s == 0) ? (t1v - t0v) : (ts[s - 1] - ts[s]);

        // ---- slot 1: prefetch next x; G1 (REG weights); xacc3 ----
        xptr += 32;
        if (s < T_STEPS - 2) {
            xn0 = *(const f32x4*)(xptr);
            xn1 = *(const f32x4*)(xptr + 4);
        }
        f32x4 xacc3[4];
        {
            f16x8 b0 = ldsA(sYb, 64, c16, (g4 << 3));
            f16x8 b1 = ldsA(sYb, 64, c16, 32 + (g4 << 3));
            #pragma unroll
            for (int t = 0; t < 2; ++t) {
                int nt = wq + 4 * t;
                if (nt < 7) {
                    f32x4 acc0 = bo1v[t];
                    f32x4 z4 = {0.f, 0.f, 0.f, 0.f};
                    acc0 = MFMA16(Wg1[t][0], b0, acc0);
                    f32x4 acc1 = MFMA16(Wg1[t][1], b1, z4);
                    int ft = nt * 16 + (g4 << 2);
                    st4(sH1, 128, c16, ft,
                        fast_tanh(acc0[0] + acc1[0]), fast_tanh(acc0[1] + acc1[1]),
                        fast_tanh(acc0[2] + acc1[2]), fast_tanh(acc0[3] + acc1[3]));
                }
            }
            #pragma unroll
            for (int q = 0; q < 4; ++q) {
                int i = wq + 4 * q;
                if (i < 14) xacc3[q] = MFMA16(Wv[(14 + bt3[q] * 3 + 2) * 64 + lane], xfrag, bzrv[q]);
            }
        }
        __syncthreads();

        // ---- slot 2: G2 (yode) + xacc5 (REG weights) ----
        f32x4 xacc5[2];
        {
            f32x4 acc0 = bo2v;
            f32x4 z4 = {0.f, 0.f, 0.f, 0.f};
            acc0 = MFMA16(Ao2[0], ldsA(sH1, 128, c16, 0 * 32 + (g4 << 3)), acc0);
            f32x4 acc1 = MFMA16(Ao2[1], ldsA(sH1, 128, c16, 1 * 32 + (g4 << 3)), z4);
            acc0 = MFMA16(Ao2[2], ldsA(sH1, 128, c16, 2 * 32 + (g4 << 3)), acc0);
            acc1 = MFMA16(Ao2[3], ldsA(sH1, 128, c16, 3 * 32 + (g4 << 3)), acc1);
            #pragma unroll
            for (int t = 0; t < 2; ++t) {
                int nt = wq + 4 * t;
                if (nt < 7) xacc5[t] = MFMA16(Wx5[t], xfrag, bh1v[t]);
            }
            #pragma unroll
            for (int r = 0; r < 4; ++r) yo[r] = y[r] + dt * (acc0[r] + acc1[r]);
            st4(sYX, 64, c16, f0, yo[0], yo[1], yo[2], yo[3]);
        }
        __syncthreads();

        // ---- slot 3: G3 (2 MFMAs/tile, C-init = x-partial) ----
        {
            f16x8 b0 = ldsA(sYX, 64, c16, (g4 << 3));
            f16x8 b1 = ldsA(sYX, 64, c16, 32 + (g4 << 3));
            #pragma unroll
            for (int q = 0; q < 4; ++q) {
                int i = wq + 4 * q;
                if (i < 14) {
                    f32x4 acc = MFMA16(Wv[(14 + bt3[q] * 3 + 0) * 64 + lane], b0, xacc3[q]);
                    acc = MFMA16(Wv[(14 + bt3[q] * 3 + 1) * 64 + lane], b1, acc);
                    int ft = bt3[q] * 16 + (g4 << 2);
                    st4(sZR, 256, c16, ft,
                        fast_tanh(acc[0]), fast_tanh(acc[1]),
                        fast_tanh(acc[2]), fast_tanh(acc[3]));
                }
            }
        }
        __syncthreads();

        // ---- slot 4: G4 (REG weights; z-gate -> regs, r-gate*yode -> sRX) ----
        {
            f32x4 accz0 = bz2v, accr0 = br2v;
            f32x4 z4 = {0.f, 0.f, 0.f, 0.f};
            f32x4 accz1 = z4, accr1 = z4;
            accz0 = MFMA16(Wg4z[0], ldsA(sZR, 256, c16, 0 * 32 + (g4 << 3)), accz0);
            accr0 = MFMA16(Wg4r[0], ldsA(sZR, 256, c16, 128 + 0 * 32 + (g4 << 3)), accr0);
            accz1 = MFMA16(Wg4z[1], ldsA(sZR, 256, c16, 1 * 32 + (g4 << 3)), accz1);
            accr1 = MFMA16(Wg4r[1], ldsA(sZR, 256, c16, 128 + 1 * 32 + (g4 << 3)), accr1);
            accz0 = MFMA16(Wg4z[2], ldsA(sZR, 256, c16, 2 * 32 + (g4 << 3)), accz0);
            accr0 = MFMA16(Wg4r[2], ldsA(sZR, 256, c16, 128 + 2 * 32 + (g4 << 3)), accr0);
            accz1 = MFMA16(Wg4z[3], ldsA(sZR, 256, c16, 3 * 32 + (g4 << 3)), accz1);
            accr1 = MFMA16(Wg4r[3], ldsA(sZR, 256, c16, 128 + 3 * 32 + (g4 << 3)), accr1);
            float rv[4];
            #pragma unroll
            for (int r = 0; r < 4; ++r) {
                zg[r] = fast_sigmoid(accz0[r] + accz1[r]);
                rv[r] = fast_sigmoid(accr0[r] + accr1[r]) * yo[r];
            }
            st4(sRX, 64, c16, f0, rv[0], rv[1], rv[2], rv[3]);
        }
        __syncthreads();

        // ---- slot 5: G5 (2 MFMAs/tile, C-init = x-partial) ----
        {
            f16x8 b0 = ldsA(sRX, 64, c16, (g4 << 3));
            f16x8 b1 = ldsA(sRX, 64, c16, 32 + (g4 << 3));
            #pragma unroll
            for (int t = 0; t < 2; ++t) {
                int nt = wq + 4 * t;
                if (nt < 7) {
                    f32x4 acc = MFMA16(Wv[(91 + nt * 3 + 0) * 64 + lane], b0, xacc5[t]);
                    acc = MFMA16(Wv[(91 + nt * 3 + 1) * 64 + lane], b1, acc);
                    int ft = nt * 16 + (g4 << 2);
                    st4(sH1, 128, c16, ft,
                        fast_tanh(acc[0]), fast_tanh(acc[1]),
                        fast_tanh(acc[2]), fast_tanh(acc[3]));
                }
            }
        }
        __syncthreads();

        // ---- slot 6: G6 (h, blend, y) ----
        {
            f32x4 acc0 = bh2v;
            f32x4 z4 = {0.f, 0.f, 0.f, 0.f};
            acc0 = MFMA16(Ah2[0], ldsA(sH1, 128, c16, 0 * 32 + (g4 << 3)), acc0);
            f32x4 acc1 = MFMA16(Ah2[1], ldsA(sH1, 128, c16, 1 * 32 + (g4 << 3)), z4);
            acc0 = MFMA16(Ah2[2], ldsA(sH1, 128, c16, 2 * 32 + (g4 << 3)), acc0);
            acc1 = MFMA16(Ah2[3], ldsA(sH1, 128, c16, 3 * 32 + (g4 << 3)), acc1);
            #pragma unroll
            for (int r = 0; r < 4; ++r) {
                float h = fast_tanh(acc0[r] + acc1[r]);
                y[r] = (1.f - zg[r]) * h + zg[r] * yo[r];
            }
            st4(sYb, 64, c16, f0, y[0], y[1], y[2], y[3]);
        }
        __syncthreads();

        xfrag = cvt8(xn0, xn1);   // pack prefetched x for next step
    }

    {
        f32x4 ov = {y[0], y[1], y[2], y[3]};
        *(f32x4*)(out + (size_t)(m0 + c16) * 64 + f0) = ov;
    }
}

extern "C" void kernel_launch(void* const* d_in, const int* in_sizes, int n_in,
                              void* d_out, int out_size, void* d_ws, size_t ws_size,
                              hipStream_t stream) {
    const float* data = (const float*)d_in[0];
    const float* ts   = (const float*)d_in[1];
    const float* prior= (const float*)d_in[2];
    const float* Wo1 = (const float*)d_in[3];  const float* bo1 = (const float*)d_in[4];
    const float* Wo2 = (const float*)d_in[5];  const float* bo2 = (const float*)d_in[6];
    const float* Wz1 = (const float*)d_in[7];  const float* bz1 = (const float*)d_in[8];
    const float* Wz2 = (const float*)d_in[9];  const float* bz2 = (const float*)d_in[10];
    const float* Wr1 = (const float*)d_in[11]; const float* br1 = (const float*)d_in[12];
    const float* Wr2 = (const float*)d_in[13]; const float* br2 = (const float*)d_in[14];
    const float* Wh1 = (const float*)d_in[15]; const float* bh1 = (const float*)d_in[16];
    const float* Wh2 = (const float*)d_in[17]; const float* bh2 = (const float*)d_in[18];
    _Float16* P = (_Float16*)d_ws;
    float* out = (float*)d_out;

    (void)hipFuncSetAttribute((const void*)odernn_kernel,
                              hipFuncAttributeMaxDynamicSharedMemorySize, LDS_TOTAL);

    hipLaunchKernelGGL(pack_kernel, dim3((144 * 512 + 255) / 256), dim3(256), 0, stream,
                       Wo1, Wo2, Wz1, Wz2, Wr1, Wr2, Wh1, Wh2, P);
    hipLaunchKernelGGL(odernn_kernel, dim3(NTRAJ / MBLK), dim3(512), LDS_TOTAL, stream,
                       data, ts, prior, bo1, bo2, bz1, bz2, br1, br2, bh1, bh2, P, out);
}

// Round 19
// 268.752 us; speedup vs baseline: 1.4111x; 1.0404x over previous
//
#include <hip/hip_runtime.h>

#define T_STEPS 100
#define NTRAJ   8192
#define MBLK    32     // two 16-row tile groups per block
#define W_TILES 112
#define W_BYTES (W_TILES * 1024)            // 114688: G1/G3/G4/G5 weights in LDS
#define TILEBUF 18432                       // per-group activation buffers
#define LDS_TOTAL (W_BYTES + 2 * TILEBUF)   // 151552 <= 163840

typedef __attribute__((ext_vector_type(8))) _Float16 f16x8;
typedef __attribute__((ext_vector_type(4))) _Float16 f16x4;
typedef __attribute__((ext_vector_type(2))) __fp16   h16x2;   // cvt_pkrtz return type
typedef __attribute__((ext_vector_type(4))) float    f32x4;

#define MFMA16(a, b, c) __builtin_amdgcn_mfma_f32_16x16x32_f16((a), (b), (c), 0, 0, 0)

// XOR swizzle on element index within a row (2B elems; XOR elem bits 3..5)
#define SWZ(row, col) ((col) ^ (((row) & 7) << 3))

// __syncthreads + __expf (R15: asm barriers / exp2f regress 22%)
__device__ __forceinline__ float fast_tanh(float x) {
    float e = __expf(2.f * x);
    return 1.f - 2.f * __builtin_amdgcn_rcpf(1.f + e);
}
__device__ __forceinline__ float fast_sigmoid(float x) {
    float e = __expf(-x);
    return __builtin_amdgcn_rcpf(1.f + e);
}

// ---------------------------------------------------------------------------
// Weight packing (UNCHANGED): tile = 512 f16, element (lane, j) = W[k][n],
// k = kt*32 + (lane>>4)*8 + j, n = nt*16 + (lane&15). A-operand of W^T.
//   [0,14) G1 | [14,30) G2 | [30,75) G3 | [75,107) G4 | [107,128) G5 | [128,144) G6
// ---------------------------------------------------------------------------
__global__ void pack_kernel(const float* __restrict__ Wo1, const float* __restrict__ Wo2,
                            const float* __restrict__ Wz1, const float* __restrict__ Wz2,
                            const float* __restrict__ Wr1, const float* __restrict__ Wr2,
                            const float* __restrict__ Wh1, const float* __restrict__ Wh2,
                            _Float16* __restrict__ P)
{
    int idx = blockIdx.x * 256 + threadIdx.x;
    if (idx >= 144 * 512) return;
    int tile = idx >> 9;
    int r    = idx & 511;
    int lane = r >> 3, j = r & 7;
    int krel = ((lane >> 4) << 3) + j;   // 0..31
    int c16  = lane & 15;
    float val = 0.f;

    if (tile < 14) {                       // ODE L1
        int t = tile, nt = t >> 1, kt = t & 1;
        int k = kt * 32 + krel, n = nt * 16 + c16;
        if (k < 64 && n < 100) val = Wo1[k * 100 + n];
    } else if (tile < 30) {                // ODE L2
        int t = tile - 14, nt = t >> 2, kt = t & 3;
        int k = kt * 32 + krel, n = nt * 16 + c16;
        if (k < 100) val = Wo2[k * 64 + n];
    } else if (tile < 75) {                // ZR L1
        int t = tile - 30, nt = t / 3, kt = t % 3;
        int k = kt * 32 + krel;            // K = 96 exact
        if (nt < 7)      { int n = nt * 16 + c16;        if (n < 100) val = Wz1[k * 100 + n]; }
        else if (nt >= 8){ int n = (nt - 8) * 16 + c16;  if (n < 100) val = Wr1[k * 100 + n]; }
    } else if (tile < 107) {               // ZR L2
        int t = tile - 75, gate = t >> 4, rem = t & 15, nt = rem >> 2, kt = rem & 3;
        int k = kt * 32 + krel, n = nt * 16 + c16;
        const float* W = gate ? Wr2 : Wz2;
        if (k < 100) val = W[k * 64 + n];
    } else if (tile < 128) {               // H L1
        int t = tile - 107, nt = t / 3, kt = t % 3;
        int k = kt * 32 + krel, n = nt * 16 + c16;
        if (n < 100) val = Wh1[k * 100 + n];
    } else {                               // H L2
        int t = tile - 128, nt = t >> 2, kt = t & 3;
        int k = kt * 32 + krel, n = nt * 16 + c16;
        if (k < 100) val = Wh2[k * 64 + n];
    }
    P[idx] = (_Float16)val;
}

// activation B-fragment read: n = traj = lane&15, k-slice contiguous 8
__device__ __forceinline__ f16x8 ldsA(const _Float16* buf, int stride, int row, int kcol) {
    return *(const f16x8*)(buf + row * stride + SWZ(row, kcol));
}
// contiguous 4-feature epilogue store (one b64)
__device__ __forceinline__ void st4(_Float16* buf, int stride, int traj, int f0,
                                    float a, float b, float c, float d) {
    f16x4 h = {(_Float16)a, (_Float16)b, (_Float16)c, (_Float16)d};
    *(f16x4*)(buf + traj * stride + SWZ(traj, f0)) = h;
}
__device__ __forceinline__ f32x4 loadBias4(const float* b, int f0, int n) {
    f32x4 v = {0.f, 0.f, 0.f, 0.f};
    #pragma unroll
    for (int r = 0; r < 4; ++r) if (f0 + r < n) v[r] = b[f0 + r];
    return v;
}
// pack 8 f32 (two f32x4) -> f16x8 via cvt_pkrtz
__device__ __forceinline__ f16x8 cvt8(f32x4 a, f32x4 b) {
    union { h16x2 h2[4]; f16x8 v; } u;
    u.h2[0] = __builtin_amdgcn_cvt_pkrtz(a[0], a[1]);
    u.h2[1] = __builtin_amdgcn_cvt_pkrtz(a[2], a[3]);
    u.h2[2] = __builtin_amdgcn_cvt_pkrtz(b[0], b[1]);
    u.h2[3] = __builtin_amdgcn_cvt_pkrtz(b[2], b[3]);
    return u.v;
}

// ---------------------------------------------------------------------------
// R17 (verified 279.6us best) + final bounded register move: Wx3 (4 frags)
// -> registers. slot-1's xacc3 MFMAs become pure-register (no lgkm dep,
// issue at slot top), and slot 1 loses its last weight LDS reads.
// Per-wave weight ds_reads 16 -> 12/step. VGPR 116 -> ~128 (clamp line).
// Spill tell: WRITE_SIZE >> 2 MB -> revert to R17.
// ---------------------------------------------------------------------------
__global__ __launch_bounds__(512, 2) void odernn_kernel(
    const float* __restrict__ data, const float* __restrict__ ts,
    const float* __restrict__ prior,
    const float* __restrict__ bo1, const float* __restrict__ bo2,
    const float* __restrict__ bz1, const float* __restrict__ bz2,
    const float* __restrict__ br1, const float* __restrict__ br2,
    const float* __restrict__ bh1, const float* __restrict__ bh2,
    const _Float16* __restrict__ P, float* __restrict__ out)
{
    extern __shared__ __align__(16) char smem[];
    _Float16* W = (_Float16*)smem;        // 112 tiles: G1[0,14) G3[14,59) G4[59,91) G5[91,112)

    const int tid  = threadIdx.x;
    const int lane = tid & 63;
    const int wv   = tid >> 6;            // 0..7
    const int tg   = wv >> 2;             // tile group 0/1
    const int wq   = wv & 3;              // wave-in-group
    const int c16  = lane & 15;           // trajectory within group
    const int g4   = lane >> 4;
    const int m0   = blockIdx.x * MBLK + tg * 16;
    const int f0   = wq * 16 + (g4 << 2); // lane's own 4-feature base (tile nt=wq)
    const f16x8* Pt = (const f16x8*)P;
    const f16x8* Wv = (const f16x8*)W;

    _Float16* base = (_Float16*)(smem + W_BYTES + tg * TILEBUF);
    _Float16* sYb = base;                 // [16][64]  y
    _Float16* sYX = base + 1024;          // [16][64]  yode
    _Float16* sRX = base + 2048;          // [16][64]  rg*yode
    _Float16* sH1 = base + 3072;          // [16][128] hidden
    _Float16* sZR = base + 5120;          // [16][256] [zh|rh] + pads

    // ---- stage G1/G3/G4/G5 weights into LDS ----
    {
        f16x8* Wd = (f16x8*)W;
        #pragma unroll
        for (int it = 0; it < 14; ++it) {
            int idx = tid + it * 512;
            int ldst = idx >> 6, l = idx & 63;
            int srct = (ldst < 14) ? ldst : ldst + 16;   // skip G2 range
            Wd[idx] = Pt[srct * 64 + l];
        }
    }

    // ---- G3/G5 tile indices for this wave ----
    int bt3[4];
    #pragma unroll
    for (int q = 0; q < 4; ++q) {
        int i = wq + 4 * q;
        bt3[q] = (i < 14) ? ((i < 7) ? i : i + 1) : 0;
    }
    const int nt1a = wq, nt1b = (wq + 4 < 7) ? wq + 4 : 6;   // G1/G5 tile ids

    // ---- biases as per-lane f32x4 feature vectors ----
    f32x4 bo1v[2], bh1v[2], bzrv[4];
    #pragma unroll
    for (int t = 0; t < 2; ++t) {
        int nt = wq + 4 * t;
        f32x4 zo = {0.f,0.f,0.f,0.f};
        if (nt < 7) {
            int ft = nt * 16 + (g4 << 2);
            bo1v[t] = loadBias4(bo1, ft, 100);
            bh1v[t] = loadBias4(bh1, ft, 100);
        } else { bo1v[t] = zo; bh1v[t] = zo; }
    }
    #pragma unroll
    for (int q = 0; q < 4; ++q) {
        int i = wq + 4 * q;
        f32x4 v = {0.f,0.f,0.f,0.f};
        if (i < 14) {
            int ft = bt3[q] * 16 + (g4 << 2);
            if (i < 7) v = loadBias4(bz1, ft, 100);
            else       v = loadBias4(br1, ft - 128, 100);
        }
        bzrv[q] = v;
    }
    const f32x4 bo2v = *(const f32x4*)(bo2 + f0);
    const f32x4 bz2v = *(const f32x4*)(bz2 + f0);
    const f32x4 br2v = *(const f32x4*)(br2 + f0);
    const f32x4 bh2v = *(const f32x4*)(bh2 + f0);

    // ---- register A-frags: G2/G6/G4/G1/G5x (R17) + G3x (new) ----
    f16x8 Ao2[4], Ah2[4], Wg4z[4], Wg4r[4], Wg1[2][2], Wx5[2], Wx3[4];
    #pragma unroll
    for (int kt = 0; kt < 4; ++kt) {
        Ao2[kt]  = Pt[(14 + wq * 4 + kt) * 64 + lane];
        Ah2[kt]  = Pt[(128 + wq * 4 + kt) * 64 + lane];
        Wg4z[kt] = Pt[(75 + wq * 4 + kt) * 64 + lane];
        Wg4r[kt] = Pt[(91 + wq * 4 + kt) * 64 + lane];
    }
    #pragma unroll
    for (int kt = 0; kt < 2; ++kt) {
        Wg1[0][kt] = Pt[(nt1a * 2 + kt) * 64 + lane];
        Wg1[1][kt] = Pt[(nt1b * 2 + kt) * 64 + lane];
    }
    Wx5[0] = Pt[(107 + nt1a * 3 + 2) * 64 + lane];
    Wx5[1] = Pt[(107 + nt1b * 3 + 2) * 64 + lane];
    #pragma unroll
    for (int q = 0; q < 4; ++q) Wx3[q] = Pt[(30 + bt3[q] * 3 + 2) * 64 + lane];

    // ---- init state ----
    float y[4], yo[4] = {0,0,0,0}, zg[4] = {0,0,0,0};
    {
        f32x4 pv = *(const f32x4*)(prior + (size_t)(m0 + c16) * 64 + f0);
        #pragma unroll
        for (int r = 0; r < 4; ++r) y[r] = pv[r];
        st4(sYb, 64, c16, f0, y[0], y[1], y[2], y[3]);
    }
    {   // sH1 pad feats 112..127, both groups (512 elems, 1/thread)
        int row32 = tid >> 4, col = 112 + (tid & 15);
        int t = row32 >> 4, r16 = row32 & 15;
        _Float16* h1 = (_Float16*)(smem + W_BYTES + t * TILEBUF) + 3072;
        h1[r16 * 128 + SWZ(r16, col)] = (_Float16)0.f;
    }
    for (int i = tid; i < 2 * 16 * 32; i += 512) {   // sZR pads, both groups
        int t = i >> 9, rem = i & 511;
        int r16 = rem >> 5, cc = rem & 31;
        int col = (cc < 16) ? (112 + cc) : (224 + cc);
        _Float16* zr = (_Float16*)(smem + W_BYTES + t * TILEBUF) + 5120;
        zr[r16 * 256 + SWZ(r16, col)] = (_Float16)0.f;
    }
    __syncthreads();

    const float t0v = ts[0], t1v = ts[1];

    // ---- x fragment: lane owns x[traj=c16][feat g4*8 .. g4*8+7] ----
    const float* xptr = data + (size_t)(m0 + c16) * (T_STEPS * 32) + 32 + (g4 << 3);
    f32x4 xn0 = *(const f32x4*)(xptr);
    f32x4 xn1 = *(const f32x4*)(xptr + 4);
    f16x8 xfrag = cvt8(xn0, xn1);

    #pragma unroll 1
    for (int s = 0; s < T_STEPS - 1; ++s) {
        const float dt = (s == 0) ? (t1v - t0v) : (ts[s - 1] - ts[s]);

        // ---- slot 1: prefetch next x; G1 (REG wts); xacc3 (REG wts) ----
        xptr += 32;
        if (s < T_STEPS - 2) {
            xn0 = *(const f32x4*)(xptr);
            xn1 = *(const f32x4*)(xptr + 4);
        }
        f32x4 xacc3[4];
        {
            f16x8 b0 = ldsA(sYb, 64, c16, (g4 << 3));
            f16x8 b1 = ldsA(sYb, 64, c16, 32 + (g4 << 3));
            #pragma unroll
            for (int q = 0; q < 4; ++q) {
                int i = wq + 4 * q;
                if (i < 14) xacc3[q] = MFMA16(Wx3[q], xfrag, bzrv[q]);
            }
            #pragma unroll
            for (int t = 0; t < 2; ++t) {
                int nt = wq + 4 * t;
                if (nt < 7) {
                    f32x4 acc0 = bo1v[t];
                    f32x4 z4 = {0.f, 0.f, 0.f, 0.f};
                    acc0 = MFMA16(Wg1[t][0], b0, acc0);
                    f32x4 acc1 = MFMA16(Wg1[t][1], b1, z4);
                    int ft = nt * 16 + (g4 << 2);
                    st4(sH1, 128, c16, ft,
                        fast_tanh(acc0[0] + acc1[0]), fast_tanh(acc0[1] + acc1[1]),
                        fast_tanh(acc0[2] + acc1[2]), fast_tanh(acc0[3] + acc1[3]));
                }
            }
        }
        __syncthreads();

        // ---- slot 2: G2 (yode) + xacc5 (REG weights) ----
        f32x4 xacc5[2];
        {
            f32x4 acc0 = bo2v;
            f32x4 z4 = {0.f, 0.f, 0.f, 0.f};
            acc0 = MFMA16(Ao2[0], ldsA(sH1, 128, c16, 0 * 32 + (g4 << 3)), acc0);
            f32x4 acc1 = MFMA16(Ao2[1], ldsA(sH1, 128, c16, 1 * 32 + (g4 << 3)), z4);
            acc0 = MFMA16(Ao2[2], ldsA(sH1, 128, c16, 2 * 32 + (g4 << 3)), acc0);
            acc1 = MFMA16(Ao2[3], ldsA(sH1, 128, c16, 3 * 32 + (g4 << 3)), acc1);
            #pragma unroll
            for (int t = 0; t < 2; ++t) {
                int nt = wq + 4 * t;
                if (nt < 7) xacc5[t] = MFMA16(Wx5[t], xfrag, bh1v[t]);
            }
            #pragma unroll
            for (int r = 0; r < 4; ++r) yo[r] = y[r] + dt * (acc0[r] + acc1[r]);
            st4(sYX, 64, c16, f0, yo[0], yo[1], yo[2], yo[3]);
        }
        __syncthreads();

        // ---- slot 3: G3 (2 MFMAs/tile, C-init = x-partial) ----
        {
            f16x8 b0 = ldsA(sYX, 64, c16, (g4 << 3));
            f16x8 b1 = ldsA(sYX, 64, c16, 32 + (g4 << 3));
            #pragma unroll
            for (int q = 0; q < 4; ++q) {
                int i = wq + 4 * q;
                if (i < 14) {
                    f32x4 acc = MFMA16(Wv[(14 + bt3[q] * 3 + 0) * 64 + lane], b0, xacc3[q]);
                    acc = MFMA16(Wv[(14 + bt3[q] * 3 + 1) * 64 + lane], b1, acc);
                    int ft = bt3[q] * 16 + (g4 << 2);
                    st4(sZR, 256, c16, ft,
                        fast_tanh(acc[0]), fast_tanh(acc[1]),
                        fast_tanh(acc[2]), fast_tanh(acc[3]));
                }
            }
        }
        __syncthreads();

        // ---- slot 4: G4 (REG weights; z-gate -> regs, r-gate*yode -> sRX) ----
        {
            f32x4 accz0 = bz2v, accr0 = br2v;
            f32x4 z4 = {0.f, 0.f, 0.f, 0.f};
            f32x4 accz1 = z4, accr1 = z4;
            accz0 = MFMA16(Wg4z[0], ldsA(sZR, 256, c16, 0 * 32 + (g4 << 3)), accz0);
            accr0 = MFMA16(Wg4r[0], ldsA(sZR, 256, c16, 128 + 0 * 32 + (g4 << 3)), accr0);
            accz1 = MFMA16(Wg4z[1], ldsA(sZR, 256, c16, 1 * 32 + (g4 << 3)), accz1);
            accr1 = MFMA16(Wg4r[1], ldsA(sZR, 256, c16, 128 + 1 * 32 + (g4 << 3)), accr1);
            accz0 = MFMA16(Wg4z[2], ldsA(sZR, 256, c16, 2 * 32 + (g4 << 3)), accz0);
            accr0 = MFMA16(Wg4r[2], ldsA(sZR, 256, c16, 128 + 2 * 32 + (g4 << 3)), accr0);
            accz1 = MFMA16(Wg4z[3], ldsA(sZR, 256, c16, 3 * 32 + (g4 << 3)), accz1);
            accr1 = MFMA16(Wg4r[3], ldsA(sZR, 256, c16, 128 + 3 * 32 + (g4 << 3)), accr1);
            float rv[4];
            #pragma unroll
            for (int r = 0; r < 4; ++r) {
                zg[r] = fast_sigmoid(accz0[r] + accz1[r]);
                rv[r] = fast_sigmoid(accr0[r] + accr1[r]) * yo[r];
            }
            st4(sRX, 64, c16, f0, rv[0], rv[1], rv[2], rv[3]);
        }
        __syncthreads();

        // ---- slot 5: G5 (2 MFMAs/tile, C-init = x-partial) ----
        {
            f16x8 b0 = ldsA(sRX, 64, c16, (g4 << 3));
            f16x8 b1 = ldsA(sRX, 64, c16, 32 + (g4 << 3));
            #pragma unroll
            for (int t = 0; t < 2; ++t) {
                int nt = wq + 4 * t;
                if (nt < 7) {
                    f32x4 acc = MFMA16(Wv[(91 + nt * 3 + 0) * 64 + lane], b0, xacc5[t]);
                    acc = MFMA16(Wv[(91 + nt * 3 + 1) * 64 + lane], b1, acc);
                    int ft = nt * 16 + (g4 << 2);
                    st4(sH1, 128, c16, ft,
                        fast_tanh(acc[0]), fast_tanh(acc[1]),
                        fast_tanh(acc[2]), fast_tanh(acc[3]));
                }
            }
        }
        __syncthreads();

        // ---- slot 6: G6 (h, blend, y) ----
        {
            f32x4 acc0 = bh2v;
            f32x4 z4 = {0.f, 0.f, 0.f, 0.f};
            acc0 = MFMA16(Ah2[0], ldsA(sH1, 128, c16, 0 * 32 + (g4 << 3)), acc0);
            f32x4 acc1 = MFMA16(Ah2[1], ldsA(sH1, 128, c16, 1 * 32 + (g4 << 3)), z4);
            acc0 = MFMA16(Ah2[2], ldsA(sH1, 128, c16, 2 * 32 + (g4 << 3)), acc0);
            acc1 = MFMA16(Ah2[3], ldsA(sH1, 128, c16, 3 * 32 + (g4 << 3)), acc1);
            #pragma unroll
            for (int r = 0; r < 4; ++r) {
                float h = fast_tanh(acc0[r] + acc1[r]);
                y[r] = (1.f - zg[r]) * h + zg[r] * yo[r];
            }
            st4(sYb, 64, c16, f0, y[0], y[1], y[2], y[3]);
        }
        __syncthreads();

        xfrag = cvt8(xn0, xn1);   // pack prefetched x for next step
    }

    {
        f32x4 ov = {y[0], y[1], y[2], y[3]};
        *(f32x4*)(out + (size_t)(m0 + c16) * 64 + f0) = ov;
    }
}

extern "C" void kernel_launch(void* const* d_in, const int* in_sizes, int n_in,
                              void* d_out, int out_size, void* d_ws, size_t ws_size,
                              hipStream_t stream) {
    const float* data = (const float*)d_in[0];
    const float* ts   = (const float*)d_in[1];
    const float* prior= (const float*)d_in[2];
    const float* Wo1 = (const float*)d_in[3];  const float* bo1 = (const float*)d_in[4];
    const float* Wo2 = (const float*)d_in[5];  const float* bo2 = (const float*)d_in[6];
    const float* Wz1 = (const float*)d_in[7];  const float* bz1 = (const float*)d_in[8];
    const float* Wz2 = (const float*)d_in[9];  const float* bz2 = (const float*)d_in[10];
    const float* Wr1 = (const float*)d_in[11]; const float* br1 = (const float*)d_in[12];
    const float* Wr2 = (const float*)d_in[13]; const float* br2 = (const float*)d_in[14];
    const float* Wh1 = (const float*)d_in[15]; const float* bh1 = (const float*)d_in[16];
    const float* Wh2 = (const float*)d_in[17]; const float* bh2 = (const float*)d_in[18];
    _Float16* P = (_Float16*)d_ws;
    float* out = (float*)d_out;

    (void)hipFuncSetAttribute((const void*)odernn_kernel,
                              hipFuncAttributeMaxDynamicSharedMemorySize, LDS_TOTAL);

    hipLaunchKernelGGL(pack_kernel, dim3((144 * 512 + 255) / 256), dim3(256), 0, stream,
                       Wo1, Wo2, Wz1, Wz2, Wr1, Wr2, Wh1, Wh2, P);
    hipLaunchKernelGGL(odernn_kernel, dim3(NTRAJ / MBLK), dim3(512), LDS_TOTAL, stream,
                       data, ts, prior, bo1, bo2, bz1, bz2, br1, br2, bh1, bh2, P, out);
}

// Round 20
// 264.944 us; speedup vs baseline: 1.4314x; 1.0144x over previous
//
#include <hip/hip_runtime.h>

#define T_STEPS 100
#define NTRAJ   8192
#define MBLK    16     // one 16-row tile group per 256-thread block
#define W_TILES 44     // live LDS weight tiles: G3 kt{0,1} (30) + G5 kt{0,1} (14)
#define W_BYTES (W_TILES * 1024)            // 45056
#define TILEBUF 18432                       // activation buffers
#define LDS_TOTAL (W_BYTES + TILEBUF)       // 63488 < 65536 -> 2 blocks/CU co-resident

typedef __attribute__((ext_vector_type(8))) _Float16 f16x8;
typedef __attribute__((ext_vector_type(4))) _Float16 f16x4;
typedef __attribute__((ext_vector_type(2))) __fp16   h16x2;   // cvt_pkrtz return type
typedef __attribute__((ext_vector_type(4))) float    f32x4;

#define MFMA16(a, b, c) __builtin_amdgcn_mfma_f32_16x16x32_f16((a), (b), (c), 0, 0, 0)

// XOR swizzle on element index within a row (2B elems; XOR elem bits 3..5)
#define SWZ(row, col) ((col) ^ (((row) & 7) << 3))

// __syncthreads + __expf (R15: asm barriers / exp2f regress 22%)
__device__ __forceinline__ float fast_tanh(float x) {
    float e = __expf(2.f * x);
    return 1.f - 2.f * __builtin_amdgcn_rcpf(1.f + e);
}
__device__ __forceinline__ float fast_sigmoid(float x) {
    float e = __expf(-x);
    return __builtin_amdgcn_rcpf(1.f + e);
}

// ---------------------------------------------------------------------------
// Weight packing (UNCHANGED): tile = 512 f16, element (lane, j) = W[k][n],
// k = kt*32 + (lane>>4)*8 + j, n = nt*16 + (lane&15). A-operand of W^T.
//   [0,14) G1 | [14,30) G2 | [30,75) G3 | [75,107) G4 | [107,128) G5 | [128,144) G6
// ---------------------------------------------------------------------------
__global__ void pack_kernel(const float* __restrict__ Wo1, const float* __restrict__ Wo2,
                            const float* __restrict__ Wz1, const float* __restrict__ Wz2,
                            const float* __restrict__ Wr1, const float* __restrict__ Wr2,
                            const float* __restrict__ Wh1, const float* __restrict__ Wh2,
                            _Float16* __restrict__ P)
{
    int idx = blockIdx.x * 256 + threadIdx.x;
    if (idx >= 144 * 512) return;
    int tile = idx >> 9;
    int r    = idx & 511;
    int lane = r >> 3, j = r & 7;
    int krel = ((lane >> 4) << 3) + j;   // 0..31
    int c16  = lane & 15;
    float val = 0.f;

    if (tile < 14) {                       // ODE L1
        int t = tile, nt = t >> 1, kt = t & 1;
        int k = kt * 32 + krel, n = nt * 16 + c16;
        if (k < 64 && n < 100) val = Wo1[k * 100 + n];
    } else if (tile < 30) {                // ODE L2
        int t = tile - 14, nt = t >> 2, kt = t & 3;
        int k = kt * 32 + krel, n = nt * 16 + c16;
        if (k < 100) val = Wo2[k * 64 + n];
    } else if (tile < 75) {                // ZR L1
        int t = tile - 30, nt = t / 3, kt = t % 3;
        int k = kt * 32 + krel;            // K = 96 exact
        if (nt < 7)      { int n = nt * 16 + c16;        if (n < 100) val = Wz1[k * 100 + n]; }
        else if (nt >= 8){ int n = (nt - 8) * 16 + c16;  if (n < 100) val = Wr1[k * 100 + n]; }
    } else if (tile < 107) {               // ZR L2
        int t = tile - 75, gate = t >> 4, rem = t & 15, nt = rem >> 2, kt = rem & 3;
        int k = kt * 32 + krel, n = nt * 16 + c16;
        const float* W = gate ? Wr2 : Wz2;
        if (k < 100) val = W[k * 64 + n];
    } else if (tile < 128) {               // H L1
        int t = tile - 107, nt = t / 3, kt = t % 3;
        int k = kt * 32 + krel, n = nt * 16 + c16;
        if (n < 100) val = Wh1[k * 100 + n];
    } else {                               // H L2
        int t = tile - 128, nt = t >> 2, kt = t & 3;
        int k = kt * 32 + krel, n = nt * 16 + c16;
        if (k < 100) val = Wh2[k * 64 + n];
    }
    P[idx] = (_Float16)val;
}

// activation B-fragment read: n = traj = lane&15, k-slice contiguous 8
__device__ __forceinline__ f16x8 ldsA(const _Float16* buf, int stride, int row, int kcol) {
    return *(const f16x8*)(buf + row * stride + SWZ(row, kcol));
}
// contiguous 4-feature epilogue store (one b64)
__device__ __forceinline__ void st4(_Float16* buf, int stride, int traj, int f0,
                                    float a, float b, float c, float d) {
    f16x4 h = {(_Float16)a, (_Float16)b, (_Float16)c, (_Float16)d};
    *(f16x4*)(buf + traj * stride + SWZ(traj, f0)) = h;
}
__device__ __forceinline__ f32x4 loadBias4(const float* b, int f0, int n) {
    f32x4 v = {0.f, 0.f, 0.f, 0.f};
    #pragma unroll
    for (int r = 0; r < 4; ++r) if (f0 + r < n) v[r] = b[f0 + r];
    return v;
}
// pack 8 f32 (two f32x4) -> f16x8 via cvt_pkrtz
__device__ __forceinline__ f16x8 cvt8(f32x4 a, f32x4 b) {
    union { h16x2 h2[4]; f16x8 v; } u;
    u.h2[0] = __builtin_amdgcn_cvt_pkrtz(a[0], a[1]);
    u.h2[1] = __builtin_amdgcn_cvt_pkrtz(a[2], a[3]);
    u.h2[2] = __builtin_amdgcn_cvt_pkrtz(b[0], b[1]);
    u.h2[3] = __builtin_amdgcn_cvt_pkrtz(b[2], b[3]);
    return u.v;
}

// ---------------------------------------------------------------------------
// R18 (verified 268.8us best) restructured into 256-thread blocks (MBLK=16):
// the register-fragment migration shrank live LDS weights to 44 tiles, so a
// block now fits in 63.5KB < 64KB -> TWO independent blocks co-reside per CU.
// Same 8 waves/CU, but barriers of the two blocks are independent -> drain
// idle of one block overlaps compute of the other (the residual ~30% idle).
// LDS pool layout: [0,30) = G3 (bt*2+kt, kt<2); [30,44) = G5 (nt*2+kt).
// ---------------------------------------------------------------------------
__global__ __launch_bounds__(256, 2) void odernn_kernel(
    const float* __restrict__ data, const float* __restrict__ ts,
    const float* __restrict__ prior,
    const float* __restrict__ bo1, const float* __restrict__ bo2,
    const float* __restrict__ bz1, const float* __restrict__ bz2,
    const float* __restrict__ br1, const float* __restrict__ br2,
    const float* __restrict__ bh1, const float* __restrict__ bh2,
    const _Float16* __restrict__ P, float* __restrict__ out)
{
    extern __shared__ __align__(16) char smem[];
    _Float16* W = (_Float16*)smem;        // 44-tile pool

    const int tid  = threadIdx.x;
    const int lane = tid & 63;
    const int wq   = tid >> 6;            // 0..3
    const int c16  = lane & 15;           // trajectory
    const int g4   = lane >> 4;
    const int m0   = blockIdx.x * MBLK;
    const int f0   = wq * 16 + (g4 << 2); // lane's own 4-feature base (tile nt=wq)
    const f16x8* Pt = (const f16x8*)P;
    const f16x8* Wv = (const f16x8*)W;

    _Float16* base = (_Float16*)(smem + W_BYTES);
    _Float16* sYb = base;                 // [16][64]  y
    _Float16* sYX = base + 1024;          // [16][64]  yode
    _Float16* sRX = base + 2048;          // [16][64]  rg*yode
    _Float16* sH1 = base + 3072;          // [16][128] hidden
    _Float16* sZR = base + 5120;          // [16][256] [zh|rh] + pads

    // ---- stage the 44 live weight tiles into LDS ----
    {
        f16x8* Wd = (f16x8*)W;
        for (int idx = tid; idx < W_TILES * 64; idx += 256) {
            int c = idx >> 6, l = idx & 63;
            int src = (c < 30) ? (30 + (c >> 1) * 3 + (c & 1))
                               : (107 + ((c - 30) >> 1) * 3 + ((c - 30) & 1));
            Wd[idx] = Pt[src * 64 + l];
        }
    }

    // ---- G3 tile indices for this wave ----
    int bt3[4];
    #pragma unroll
    for (int q = 0; q < 4; ++q) {
        int i = wq + 4 * q;
        bt3[q] = (i < 14) ? ((i < 7) ? i : i + 1) : 0;
    }
    const int nt1a = wq, nt1b = (wq + 4 < 7) ? wq + 4 : 6;   // G1/G5 tile ids

    // ---- biases as per-lane f32x4 feature vectors ----
    f32x4 bo1v[2], bh1v[2], bzrv[4];
    #pragma unroll
    for (int t = 0; t < 2; ++t) {
        int nt = wq + 4 * t;
        f32x4 zo = {0.f,0.f,0.f,0.f};
        if (nt < 7) {
            int ft = nt * 16 + (g4 << 2);
            bo1v[t] = loadBias4(bo1, ft, 100);
            bh1v[t] = loadBias4(bh1, ft, 100);
        } else { bo1v[t] = zo; bh1v[t] = zo; }
    }
    #pragma unroll
    for (int q = 0; q < 4; ++q) {
        int i = wq + 4 * q;
        f32x4 v = {0.f,0.f,0.f,0.f};
        if (i < 14) {
            int ft = bt3[q] * 16 + (g4 << 2);
            if (i < 7) v = loadBias4(bz1, ft, 100);
            else       v = loadBias4(br1, ft - 128, 100);
        }
        bzrv[q] = v;
    }
    const f32x4 bo2v = *(const f32x4*)(bo2 + f0);
    const f32x4 bz2v = *(const f32x4*)(bz2 + f0);
    const f32x4 br2v = *(const f32x4*)(br2 + f0);
    const f32x4 bh2v = *(const f32x4*)(bh2 + f0);

    // ---- register A-frags (all but G3/G5 kt{0,1}) ----
    f16x8 Ao2[4], Ah2[4], Wg4z[4], Wg4r[4], Wg1[2][2], Wx5[2], Wx3[4];
    #pragma unroll
    for (int kt = 0; kt < 4; ++kt) {
        Ao2[kt]  = Pt[(14 + wq * 4 + kt) * 64 + lane];
        Ah2[kt]  = Pt[(128 + wq * 4 + kt) * 64 + lane];
        Wg4z[kt] = Pt[(75 + wq * 4 + kt) * 64 + lane];
        Wg4r[kt] = Pt[(91 + wq * 4 + kt) * 64 + lane];
    }
    #pragma unroll
    for (int kt = 0; kt < 2; ++kt) {
        Wg1[0][kt] = Pt[(nt1a * 2 + kt) * 64 + lane];
        Wg1[1][kt] = Pt[(nt1b * 2 + kt) * 64 + lane];
    }
    Wx5[0] = Pt[(107 + nt1a * 3 + 2) * 64 + lane];
    Wx5[1] = Pt[(107 + nt1b * 3 + 2) * 64 + lane];
    #pragma unroll
    for (int q = 0; q < 4; ++q) Wx3[q] = Pt[(30 + bt3[q] * 3 + 2) * 64 + lane];

    // ---- init state ----
    float y[4], yo[4] = {0,0,0,0}, zg[4] = {0,0,0,0};
    {
        f32x4 pv = *(const f32x4*)(prior + (size_t)(m0 + c16) * 64 + f0);
        #pragma unroll
        for (int r = 0; r < 4; ++r) y[r] = pv[r];
        st4(sYb, 64, c16, f0, y[0], y[1], y[2], y[3]);
    }
    {   // sH1 pad feats 112..127 (256 elems, 1/thread)
        int row = tid >> 4, col = 112 + (tid & 15);
        sH1[row * 128 + SWZ(row, col)] = (_Float16)0.f;
    }
    for (int i = tid; i < 16 * 32; i += 256) {   // sZR pads
        int r16 = i >> 5, cc = i & 31;
        int col = (cc < 16) ? (112 + cc) : (224 + cc);
        sZR[r16 * 256 + SWZ(r16, col)] = (_Float16)0.f;
    }
    __syncthreads();

    const float t0v = ts[0], t1v = ts[1];

    // ---- x fragment: lane owns x[traj=c16][feat g4*8 .. g4*8+7] ----
    const float* xptr = data + (size_t)(m0 + c16) * (T_STEPS * 32) + 32 + (g4 << 3);
    f32x4 xn0 = *(const f32x4*)(xptr);
    f32x4 xn1 = *(const f32x4*)(xptr + 4);
    f16x8 xfrag = cvt8(xn0, xn1);

    #pragma unroll 1
    for (int s = 0; s < T_STEPS - 1; ++s) {
        const float dt = (s == 0) ? (t1v - t0v) : (ts[s - 1] - ts[s]);

        // ---- slot 1: prefetch next x; G1 (REG wts); xacc3 (REG wts) ----
        xptr += 32;
        if (s < T_STEPS - 2) {
            xn0 = *(const f32x4*)(xptr);
            xn1 = *(const f32x4*)(xptr + 4);
        }
        f32x4 xacc3[4];
        {
            f16x8 b0 = ldsA(sYb, 64, c16, (g4 << 3));
            f16x8 b1 = ldsA(sYb, 64, c16, 32 + (g4 << 3));
            #pragma unroll
            for (int q = 0; q < 4; ++q) {
                int i = wq + 4 * q;
                if (i < 14) xacc3[q] = MFMA16(Wx3[q], xfrag, bzrv[q]);
            }
            #pragma unroll
            for (int t = 0; t < 2; ++t) {
                int nt = wq + 4 * t;
                if (nt < 7) {
                    f32x4 acc0 = bo1v[t];
                    f32x4 z4 = {0.f, 0.f, 0.f, 0.f};
                    acc0 = MFMA16(Wg1[t][0], b0, acc0);
                    f32x4 acc1 = MFMA16(Wg1[t][1], b1, z4);
                    int ft = nt * 16 + (g4 << 2);
                    st4(sH1, 128, c16, ft,
                        fast_tanh(acc0[0] + acc1[0]), fast_tanh(acc0[1] + acc1[1]),
                        fast_tanh(acc0[2] + acc1[2]), fast_tanh(acc0[3] + acc1[3]));
                }
            }
        }
        __syncthreads();

        // ---- slot 2: G2 (yode) + xacc5 (REG weights) ----
        f32x4 xacc5[2];
        {
            f32x4 acc0 = bo2v;
            f32x4 z4 = {0.f, 0.f, 0.f, 0.f};
            acc0 = MFMA16(Ao2[0], ldsA(sH1, 128, c16, 0 * 32 + (g4 << 3)), acc0);
            f32x4 acc1 = MFMA16(Ao2[1], ldsA(sH1, 128, c16, 1 * 32 + (g4 << 3)), z4);
            acc0 = MFMA16(Ao2[2], ldsA(sH1, 128, c16, 2 * 32 + (g4 << 3)), acc0);
            acc1 = MFMA16(Ao2[3], ldsA(sH1, 128, c16, 3 * 32 + (g4 << 3)), acc1);
            #pragma unroll
            for (int t = 0; t < 2; ++t) {
                int nt = wq + 4 * t;
                if (nt < 7) xacc5[t] = MFMA16(Wx5[t], xfrag, bh1v[t]);
            }
            #pragma unroll
            for (int r = 0; r < 4; ++r) yo[r] = y[r] + dt * (acc0[r] + acc1[r]);
            st4(sYX, 64, c16, f0, yo[0], yo[1], yo[2], yo[3]);
        }
        __syncthreads();

        // ---- slot 3: G3 (2 MFMAs/tile from pool, C-init = x-partial) ----
        {
            f16x8 b0 = ldsA(sYX, 64, c16, (g4 << 3));
            f16x8 b1 = ldsA(sYX, 64, c16, 32 + (g4 << 3));
            #pragma unroll
            for (int q = 0; q < 4; ++q) {
                int i = wq + 4 * q;
                if (i < 14) {
                    f32x4 acc = MFMA16(Wv[(bt3[q] * 2 + 0) * 64 + lane], b0, xacc3[q]);
                    acc = MFMA16(Wv[(bt3[q] * 2 + 1) * 64 + lane], b1, acc);
                    int ft = bt3[q] * 16 + (g4 << 2);
                    st4(sZR, 256, c16, ft,
                        fast_tanh(acc[0]), fast_tanh(acc[1]),
                        fast_tanh(acc[2]), fast_tanh(acc[3]));
                }
            }
        }
        __syncthreads();

        // ---- slot 4: G4 (REG weights; z-gate -> regs, r-gate*yode -> sRX) ----
        {
            f32x4 accz0 = bz2v, accr0 = br2v;
            f32x4 z4 = {0.f, 0.f, 0.f, 0.f};
            f32x4 accz1 = z4, accr1 = z4;
            accz0 = MFMA16(Wg4z[0], ldsA(sZR, 256, c16, 0 * 32 + (g4 << 3)), accz0);
            accr0 = MFMA16(Wg4r[0], ldsA(sZR, 256, c16, 128 + 0 * 32 + (g4 << 3)), accr0);
            accz1 = MFMA16(Wg4z[1], ldsA(sZR, 256, c16, 1 * 32 + (g4 << 3)), accz1);
            accr1 = MFMA16(Wg4r[1], ldsA(sZR, 256, c16, 128 + 1 * 32 + (g4 << 3)), accr1);
            accz0 = MFMA16(Wg4z[2], ldsA(sZR, 256, c16, 2 * 32 + (g4 << 3)), accz0);
            accr0 = MFMA16(Wg4r[2], ldsA(sZR, 256, c16, 128 + 2 * 32 + (g4 << 3)), accr0);
            accz1 = MFMA16(Wg4z[3], ldsA(sZR, 256, c16, 3 * 32 + (g4 << 3)), accz1);
            accr1 = MFMA16(Wg4r[3], ldsA(sZR, 256, c16, 128 + 3 * 32 + (g4 << 3)), accr1);
            float rv[4];
            #pragma unroll
            for (int r = 0; r < 4; ++r) {
                zg[r] = fast_sigmoid(accz0[r] + accz1[r]);
                rv[r] = fast_sigmoid(accr0[r] + accr1[r]) * yo[r];
            }
            st4(sRX, 64, c16, f0, rv[0], rv[1], rv[2], rv[3]);
        }
        __syncthreads();

        // ---- slot 5: G5 (2 MFMAs/tile from pool, C-init = x-partial) ----
        {
            f16x8 b0 = ldsA(sRX, 64, c16, (g4 << 3));
            f16x8 b1 = ldsA(sRX, 64, c16, 32 + (g4 << 3));
            #pragma unroll
            for (int t = 0; t < 2; ++t) {
                int nt = wq + 4 * t;
                if (nt < 7) {
                    f32x4 acc = MFMA16(Wv[(30 + nt * 2 + 0) * 64 + lane], b0, xacc5[t]);
                    acc = MFMA16(Wv[(30 + nt * 2 + 1) * 64 + lane], b1, acc);
                    int ft = nt * 16 + (g4 << 2);
                    st4(sH1, 128, c16, ft,
                        fast_tanh(acc[0]), fast_tanh(acc[1]),
                        fast_tanh(acc[2]), fast_tanh(acc[3]));
                }
            }
        }
        __syncthreads();

        // ---- slot 6: G6 (h, blend, y) ----
        {
            f32x4 acc0 = bh2v;
            f32x4 z4 = {0.f, 0.f, 0.f, 0.f};
            acc0 = MFMA16(Ah2[0], ldsA(sH1, 128, c16, 0 * 32 + (g4 << 3)), acc0);
            f32x4 acc1 = MFMA16(Ah2[1], ldsA(sH1, 128, c16, 1 * 32 + (g4 << 3)), z4);
            acc0 = MFMA16(Ah2[2], ldsA(sH1, 128, c16, 2 * 32 + (g4 << 3)), acc0);
            acc1 = MFMA16(Ah2[3], ldsA(sH1, 128, c16, 3 * 32 + (g4 << 3)), acc1);
            #pragma unroll
            for (int r = 0; r < 4; ++r) {
                float h = fast_tanh(acc0[r] + acc1[r]);
                y[r] = (1.f - zg[r]) * h + zg[r] * yo[r];
            }
            st4(sYb, 64, c16, f0, y[0], y[1], y[2], y[3]);
        }
        __syncthreads();

        xfrag = cvt8(xn0, xn1);   // pack prefetched x for next step
    }

    {
        f32x4 ov = {y[0], y[1], y[2], y[3]};
        *(f32x4*)(out + (size_t)(m0 + c16) * 64 + f0) = ov;
    }
}

extern "C" void kernel_launch(void* const* d_in, const int* in_sizes, int n_in,
                              void* d_out, int out_size, void* d_ws, size_t ws_size,
                              hipStream_t stream) {
    const float* data = (const float*)d_in[0];
    const float* ts   = (const float*)d_in[1];
    const float* prior= (const float*)d_in[2];
    const float* Wo1 = (const float*)d_in[3];  const float* bo1 = (const float*)d_in[4];
    const float* Wo2 = (const float*)d_in[5];  const float* bo2 = (const float*)d_in[6];
    const float* Wz1 = (const float*)d_in[7];  const float* bz1 = (const float*)d_in[8];
    const float* Wz2 = (const float*)d_in[9];  const float* bz2 = (const float*)d_in[10];
    const float* Wr1 = (const float*)d_in[11]; const float* br1 = (const float*)d_in[12];
    const float* Wr2 = (const float*)d_in[13]; const float* br2 = (const float*)d_in[14];
    const float* Wh1 = (const float*)d_in[15]; const float* bh1 = (const float*)d_in[16];
    const float* Wh2 = (const float*)d_in[17]; const float* bh2 = (const float*)d_in[18];
    _Float16* P = (_Float16*)d_ws;
    float* out = (float*)d_out;

    hipLaunchKernelGGL(pack_kernel, dim3((144 * 512 + 255) / 256), dim3(256), 0, stream,
                       Wo1, Wo2, Wz1, Wz2, Wr1, Wr2, Wh1, Wh2, P);
    hipLaunchKernelGGL(odernn_kernel, dim3(NTRAJ / MBLK), dim3(256), LDS_TOTAL, stream,
                       data, ts, prior, bo1, bo2, bz1, bz2, br1, br2, bh1, bh2, P, out);
}